// Round 6
// baseline (2121.527 us; speedup 1.0000x reference)
//
#include <hip/hip_runtime.h>
#include <math.h>

#define Bz 32
#define Tz 512
#define Dz 1024
#define Pz 512
#define Ez 256
#define KC 14
#define NHz 4
#define Lz 2
#define FFz 2048
#define TOPKz 7
#define EPSz 1e-5f
#define BT (Bz*Tz)

typedef unsigned short ushort_t;
typedef __attribute__((ext_vector_type(8))) short short8;
typedef __attribute__((ext_vector_type(4))) float f32x4;

__device__ __forceinline__ ushort_t f2bf(float f) {
    union { float f; unsigned int u; } x; x.f = f;
    unsigned int r = x.u + 0x7fffu + ((x.u >> 16) & 1u);   // RNE (finite inputs)
    return (ushort_t)(r >> 16);
}

// =================== 8-phase 256x256 bf16 MFMA GEMM (m201-style, plain HIP) ===================
// C = A[M,K]bf16 @ W^T[N,K]bf16. 8 waves (2Mx4N), BK=64, 128KB LDS dbuf, st_16x32 swizzle,
// counted vmcnt, setprio around MFMA clusters. M,N mult of 256; K mult of 64, K>=128.
__global__ __launch_bounds__(512, 2) void mgemm8_k(
    const ushort_t* __restrict__ A, int lda,
    const ushort_t* __restrict__ Wt,                  // [N][Kd]
    const float* __restrict__ bias,
    float* __restrict__ Cf, ushort_t* __restrict__ Ch, int ldc,
    int Kd, int epi,
    const float* __restrict__ bng, const float* __restrict__ bnb,
    const float* __restrict__ bnm, const float* __restrict__ bnv)
{
    __shared__ __align__(16) ushort_t AsB[2][256 * 64];
    __shared__ __align__(16) ushort_t BsB[2][256 * 64];
    const int tid = threadIdx.x;
    const int lane = tid & 63, w = tid >> 6;          // 8 waves
    const int wr = w >> 2, wc = w & 3;                // 2 x 4
    const int row0 = blockIdx.y * 256, col0 = blockIdx.x * 256;
    const int T = Kd >> 6;                            // K-tiles of 64

    // staging: per half-tile, 2 global_load_lds per thread; LDS dest = uniform base + lane*16.
    // source col pre-swizzled (inverse of st_16x32): row bit2 == lane bit5.
    const int colE = ((lane & 7) * 8) ^ ((lane & 32) ? 16 : 0);   // element offset in K-dir

    auto STAGE_A = [&](int k, int hf) {               // hf: 0 -> rows {0-63,128-191}, 1 -> +64
        const int buf = k & 1;
        #pragma unroll
        for (int i = 0; i < 2; i++) {
            const int rbu = hf * 64 + i * 128 + w * 8;          // wave-uniform row base
            const int row = rbu + (lane >> 3);
            const ushort_t* g = A + (size_t)(row0 + row) * lda + k * 64 + colE;
            ushort_t* l = AsB[buf] + rbu * 64;
            __builtin_amdgcn_global_load_lds(
                (const __attribute__((address_space(1))) unsigned int*)g,
                (__attribute__((address_space(3))) unsigned int*)l, 16, 0, 0);
        }
    };
    auto STAGE_B = [&](int k, int hf) {               // hf: 0 -> rows ==0..31 mod 64, 1 -> +32
        const int buf = k & 1;
        #pragma unroll
        for (int i = 0; i < 2; i++) {
            const int rbu = i * 128 + (w >> 2) * 64 + (w & 3) * 8 + hf * 32;
            const int row = rbu + (lane >> 3);
            const ushort_t* g = Wt + (size_t)(col0 + row) * Kd + k * 64 + colE;
            ushort_t* l = BsB[buf] + rbu * 64;
            __builtin_amdgcn_global_load_lds(
                (const __attribute__((address_space(1))) unsigned int*)g,
                (__attribute__((address_space(3))) unsigned int*)l, 16, 0, 0);
        }
    };

    // prologue: stage tiles 0 and 1 fully; keep tile1 (8 loads) in flight past the wait
    STAGE_A(0, 0); STAGE_A(0, 1); STAGE_B(0, 0); STAGE_B(0, 1);
    STAGE_A(1, 0); STAGE_A(1, 1); STAGE_B(1, 0); STAGE_B(1, 1);
    asm volatile("s_waitcnt vmcnt(8)" ::: "memory");
    __builtin_amdgcn_s_barrier();

    f32x4 acc[8][4];
    const f32x4 zr = {0.f, 0.f, 0.f, 0.f};
    #pragma unroll
    for (int m = 0; m < 8; m++)
        #pragma unroll
        for (int n = 0; n < 4; n++) acc[m][n] = zr;

    const int cbband = ((lane >> 2) & 1) << 5;        // read-side swizzle term (bytes)
    const int cbase = (lane >> 4) * 16;               // byte col within 64B k-slice

    for (int t = 0; t < T; t++) {
        const ushort_t* Ab = AsB[t & 1];
        const ushort_t* Bb = BsB[t & 1];
        short8 af[4][2], bf0[2][2], bf1[2][2];

        auto LDA = [&](int mh) {
            #pragma unroll
            for (int m2 = 0; m2 < 4; m2++) {
                const int r = wr * 128 + mh * 64 + m2 * 16 + (lane & 15);
                const char* rp = (const char*)Ab + (size_t)r * 128;
                #pragma unroll
                for (int ks = 0; ks < 2; ks++)
                    af[m2][ks] = *(const short8*)(rp + ((ks * 64 + cbase) ^ cbband));
            }
        };
        auto LDB = [&](short8 (*dst)[2], int nh) {
            #pragma unroll
            for (int n2 = 0; n2 < 2; n2++) {
                const int r = wc * 64 + nh * 32 + n2 * 16 + (lane & 15);
                const char* rp = (const char*)Bb + (size_t)r * 128;
                #pragma unroll
                for (int ks = 0; ks < 2; ks++)
                    dst[n2][ks] = *(const short8*)(rp + ((ks * 64 + cbase) ^ cbband));
            }
        };

        // ---- phase 0: quadrant (mh=0, nh=0) ----
        LDA(0); LDB(bf0, 0);
        if (t >= 1 && t + 1 < T) STAGE_A(t + 1, 1);
        __builtin_amdgcn_s_barrier();
        __builtin_amdgcn_s_setprio(1);
        #pragma unroll
        for (int m2 = 0; m2 < 4; m2++)
            #pragma unroll
            for (int n2 = 0; n2 < 2; n2++)
                #pragma unroll
                for (int ks = 0; ks < 2; ks++)
                    acc[m2][n2] = __builtin_amdgcn_mfma_f32_16x16x32_bf16(af[m2][ks], bf0[n2][ks], acc[m2][n2], 0, 0, 0);
        __builtin_amdgcn_s_setprio(0);
        __builtin_amdgcn_s_barrier();

        // ---- phase 1: (mh=0, nh=1) ----
        LDB(bf1, 1);
        if (t >= 1 && t + 1 < T) STAGE_B(t + 1, 1);
        __builtin_amdgcn_s_barrier();
        __builtin_amdgcn_s_setprio(1);
        #pragma unroll
        for (int m2 = 0; m2 < 4; m2++)
            #pragma unroll
            for (int n2 = 0; n2 < 2; n2++)
                #pragma unroll
                for (int ks = 0; ks < 2; ks++)
                    acc[m2][2 + n2] = __builtin_amdgcn_mfma_f32_16x16x32_bf16(af[m2][ks], bf1[n2][ks], acc[m2][2 + n2], 0, 0, 0);
        __builtin_amdgcn_s_setprio(0);
        __builtin_amdgcn_s_barrier();

        // ---- phase 2: (mh=1, nh=0) --- A-h0 rows of THIS buf now free -> stage tile t+2 ----
        LDA(1);
        if (t + 2 < T) STAGE_A(t + 2, 0);
        __builtin_amdgcn_s_barrier();
        __builtin_amdgcn_s_setprio(1);
        #pragma unroll
        for (int m2 = 0; m2 < 4; m2++)
            #pragma unroll
            for (int n2 = 0; n2 < 2; n2++)
                #pragma unroll
                for (int ks = 0; ks < 2; ks++)
                    acc[4 + m2][n2] = __builtin_amdgcn_mfma_f32_16x16x32_bf16(af[m2][ks], bf0[n2][ks], acc[4 + m2][n2], 0, 0, 0);
        __builtin_amdgcn_s_setprio(0);
        __builtin_amdgcn_s_barrier();

        // ---- phase 3: (mh=1, nh=1) ----
        if (t + 2 < T) STAGE_B(t + 2, 0);
        __builtin_amdgcn_s_barrier();
        __builtin_amdgcn_s_setprio(1);
        #pragma unroll
        for (int m2 = 0; m2 < 4; m2++)
            #pragma unroll
            for (int n2 = 0; n2 < 2; n2++)
                #pragma unroll
                for (int ks = 0; ks < 2; ks++)
                    acc[4 + m2][2 + n2] = __builtin_amdgcn_mfma_f32_16x16x32_bf16(af[m2][ks], bf1[n2][ks], acc[4 + m2][2 + n2], 0, 0, 0);
        __builtin_amdgcn_s_setprio(0);
        // boundary: tile t+1 must be resident; allowed in flight = t+2's 2 halves (4 loads)
        if (t + 2 < T) { asm volatile("s_waitcnt vmcnt(4)" ::: "memory"); }
        else           { asm volatile("s_waitcnt vmcnt(0)" ::: "memory"); }
        __builtin_amdgcn_s_barrier();
    }

    // ---- epilogue: bias / BN / relu, dual fp32+bf16 out ----
    #pragma unroll
    for (int ni = 0; ni < 4; ni++) {
        const int ccol = col0 + wc * 64 + ni * 16 + (lane & 15);
        const float bb = bias[ccol];
        float bsc = 1.f, bsh = 0.f;
        if (epi == 2) {
            bsc = rsqrtf(bnv[ccol] + EPSz) * bng[ccol];
            bsh = bnb[ccol] - bnm[ccol] * bsc;
        }
        #pragma unroll
        for (int mi = 0; mi < 8; mi++) {
            #pragma unroll
            for (int r = 0; r < 4; r++) {
                const int crow = row0 + wr * 128 + mi * 16 + (lane >> 4) * 4 + r;
                float y = acc[mi][ni][r] + bb;
                if (epi == 2) y = y * bsc + bsh;
                if (epi >= 1) y = fmaxf(y, 0.f);
                if (Cf) Cf[(size_t)crow * ldc + ccol] = y;
                if (Ch) Ch[(size_t)crow * ldc + ccol] = f2bf(y);
            }
        }
    }
}

// ---------------- 128x128 bf16 MFMA GEMM (m97 structure) for small N / K -----------------------
__global__ __launch_bounds__(256) void mgemm_k(
    const ushort_t* __restrict__ A, int lda,
    const ushort_t* __restrict__ Wt,
    const float* __restrict__ bias,
    float* __restrict__ Cf, ushort_t* __restrict__ Ch, int ldc,
    int Kd, int epi,
    const float* __restrict__ bng, const float* __restrict__ bnb,
    const float* __restrict__ bnm, const float* __restrict__ bnv)
{
    __shared__ __align__(16) ushort_t As[128 * 32];
    __shared__ __align__(16) ushort_t Bs[128 * 32];
    const int tid = threadIdx.x;
    const int lane = tid & 63, wid = tid >> 6;
    const int row0 = blockIdx.y * 128, col0 = blockIdx.x * 128;
    const int wrow = (wid >> 1) * 64, wcol = (wid & 1) * 64;
    const int srow = (lane >> 2);
    const int skoff = (lane & 3) * 8;

    f32x4 acc[4][4];
    const f32x4 zr = {0.f, 0.f, 0.f, 0.f};
    #pragma unroll
    for (int m = 0; m < 4; m++)
        #pragma unroll
        for (int n = 0; n < 4; n++) acc[m][n] = zr;

    for (int k0 = 0; k0 < Kd; k0 += 32) {
        #pragma unroll
        for (int j = 0; j < 2; j++) {
            const int r = wid * 32 + j * 16;
            const ushort_t* ga = A + (size_t)(row0 + r + srow) * lda + k0 + skoff;
            __builtin_amdgcn_global_load_lds(
                (const __attribute__((address_space(1))) unsigned int*)ga,
                (__attribute__((address_space(3))) unsigned int*)(As + r * 32), 16, 0, 0);
            const ushort_t* gb = Wt + (size_t)(col0 + r + srow) * Kd + k0 + skoff;
            __builtin_amdgcn_global_load_lds(
                (const __attribute__((address_space(1))) unsigned int*)gb,
                (__attribute__((address_space(3))) unsigned int*)(Bs + r * 32), 16, 0, 0);
        }
        __syncthreads();
        short8 af[4], bf[4];
        #pragma unroll
        for (int m = 0; m < 4; m++)
            af[m] = *(const short8*)(As + (wrow + m * 16 + (lane & 15)) * 32 + (lane >> 4) * 8);
        #pragma unroll
        for (int n = 0; n < 4; n++)
            bf[n] = *(const short8*)(Bs + (wcol + n * 16 + (lane & 15)) * 32 + (lane >> 4) * 8);
        #pragma unroll
        for (int m = 0; m < 4; m++)
            #pragma unroll
            for (int n = 0; n < 4; n++)
                acc[m][n] = __builtin_amdgcn_mfma_f32_16x16x32_bf16(af[m], bf[n], acc[m][n], 0, 0, 0);
        __syncthreads();
    }

    #pragma unroll
    for (int n = 0; n < 4; n++) {
        const int ccol = col0 + wcol + n * 16 + (lane & 15);
        const float bb = bias[ccol];
        float bsc = 1.f, bsh = 0.f;
        if (epi == 2) {
            bsc = rsqrtf(bnv[ccol] + EPSz) * bng[ccol];
            bsh = bnb[ccol] - bnm[ccol] * bsc;
        }
        #pragma unroll
        for (int m = 0; m < 4; m++) {
            #pragma unroll
            for (int r = 0; r < 4; r++) {
                const int crow = row0 + wrow + m * 16 + (lane >> 4) * 4 + r;
                float y = acc[m][n][r] + bb;
                if (epi == 2) y = y * bsc + bsh;
                if (epi >= 1) y = fmaxf(y, 0.f);
                if (Cf) Cf[(size_t)crow * ldc + ccol] = y;
                if (Ch) Ch[(size_t)crow * ldc + ccol] = f2bf(y);
            }
        }
    }
}

// ---------------- batched bf16 MFMA GEMM over z=(batch,head): fp32 OR bf16 out -----------------
__global__ __launch_bounds__(256) void bgemm_k(
    const ushort_t* __restrict__ A0, int lda, size_t Abz, int Ahz,
    const ushort_t* __restrict__ W0, int ldw, size_t Wbz, int Whz,
    float* __restrict__ Cf0, ushort_t* __restrict__ Ch0, int ldc, size_t Cbz, int Chz, int Kd)
{
    const int z = blockIdx.z, bl = z >> 2, hh = z & 3;
    const ushort_t* A = A0 + (size_t)bl * Abz + (size_t)hh * Ahz;
    const ushort_t* W = W0 + (size_t)bl * Wbz + (size_t)hh * Whz;

    __shared__ __align__(16) ushort_t As[128 * 32];
    __shared__ __align__(16) ushort_t Bs[128 * 32];
    const int tid = threadIdx.x;
    const int lane = tid & 63, wid = tid >> 6;
    const int row0 = blockIdx.y * 128, col0 = blockIdx.x * 128;
    const int wrow = (wid >> 1) * 64, wcol = (wid & 1) * 64;
    const int srow = (lane >> 2);
    const int skoff = (lane & 3) * 8;

    f32x4 acc[4][4];
    const f32x4 zr = {0.f, 0.f, 0.f, 0.f};
    #pragma unroll
    for (int m = 0; m < 4; m++)
        #pragma unroll
        for (int n = 0; n < 4; n++) acc[m][n] = zr;

    for (int k0 = 0; k0 < Kd; k0 += 32) {
        #pragma unroll
        for (int j = 0; j < 2; j++) {
            const int r = wid * 32 + j * 16;
            const ushort_t* ga = A + (size_t)(row0 + r + srow) * lda + k0 + skoff;
            __builtin_amdgcn_global_load_lds(
                (const __attribute__((address_space(1))) unsigned int*)ga,
                (__attribute__((address_space(3))) unsigned int*)(As + r * 32), 16, 0, 0);
            const ushort_t* gb = W + (size_t)(col0 + r + srow) * ldw + k0 + skoff;
            __builtin_amdgcn_global_load_lds(
                (const __attribute__((address_space(1))) unsigned int*)gb,
                (__attribute__((address_space(3))) unsigned int*)(Bs + r * 32), 16, 0, 0);
        }
        __syncthreads();
        short8 af[4], bf[4];
        #pragma unroll
        for (int m = 0; m < 4; m++)
            af[m] = *(const short8*)(As + (wrow + m * 16 + (lane & 15)) * 32 + (lane >> 4) * 8);
        #pragma unroll
        for (int n = 0; n < 4; n++)
            bf[n] = *(const short8*)(Bs + (wcol + n * 16 + (lane & 15)) * 32 + (lane >> 4) * 8);
        #pragma unroll
        for (int m = 0; m < 4; m++)
            #pragma unroll
            for (int n = 0; n < 4; n++)
                acc[m][n] = __builtin_amdgcn_mfma_f32_16x16x32_bf16(af[m], bf[n], acc[m][n], 0, 0, 0);
        __syncthreads();
    }

    #pragma unroll
    for (int n = 0; n < 4; n++) {
        const int ccol = col0 + wcol + n * 16 + (lane & 15);
        #pragma unroll
        for (int m = 0; m < 4; m++) {
            #pragma unroll
            for (int r = 0; r < 4; r++) {
                const int crow = row0 + wrow + m * 16 + (lane >> 4) * 4 + r;
                const float y = acc[m][n][r];
                if (Cf0) (Cf0 + (size_t)bl * Cbz + (size_t)hh * Chz)[(size_t)crow * ldc + ccol] = y;
                if (Ch0) (Ch0 + (size_t)bl * Cbz + (size_t)hh * Chz)[(size_t)crow * ldc + ccol] = f2bf(y);
            }
        }
    }
}

// ------------- softmax over S rows (scale 1/16), write normalized P in bf16 --------------------
__global__ __launch_bounds__(256) void softmax_k(
    const float* __restrict__ S, ushort_t* __restrict__ P)
{
    const int row = blockIdx.x * 4 + (threadIdx.x >> 6);
    const int lane = threadIdx.x & 63;
    const float* sr = S + (size_t)row * 512 + lane * 8;
    const float4 a = *(const float4*)sr;
    const float4 b = *(const float4*)(sr + 4);
    float v[8] = {a.x, a.y, a.z, a.w, b.x, b.y, b.z, b.w};
    #pragma unroll
    for (int i = 0; i < 8; i++) v[i] *= 0.0625f;
    float m = v[0];
    #pragma unroll
    for (int i = 1; i < 8; i++) m = fmaxf(m, v[i]);
    #pragma unroll
    for (int off = 32; off > 0; off >>= 1) m = fmaxf(m, __shfl_xor(m, off));
    float s = 0.f;
    #pragma unroll
    for (int i = 0; i < 8; i++) { v[i] = expf(v[i] - m); s += v[i]; }
    #pragma unroll
    for (int off = 32; off > 0; off >>= 1) s += __shfl_xor(s, off);
    const float inv = 1.f / s;
    union { ushort_t h[8]; uint4 u; } pk;
    #pragma unroll
    for (int i = 0; i < 8; i++) pk.h[i] = f2bf(v[i] * inv);
    *(uint4*)(P + (size_t)row * 512 + lane * 8) = pk.u;
}

// ------------- z-batched bf16 transpose: V[kv][d] (qkvb v-slots) -> Vt[d][kv] ------------------
__global__ __launch_bounds__(256) void vtb_k(
    const ushort_t* __restrict__ qkvb, ushort_t* __restrict__ Vt)
{
    const int z = blockIdx.z, bl = z >> 2, hh = z & 3;
    const ushort_t* src = qkvb + (size_t)bl * 512 * 3072 + 2048 + hh * 256;
    ushort_t* dst = Vt + (size_t)z * 256 * 512;
    __shared__ ushort_t t[32][33];
    const int tx = threadIdx.x & 31, ty = threadIdx.x >> 5;
    const int gx = blockIdx.x * 32;   // d
    const int gy = blockIdx.y * 32;   // kv
    #pragma unroll
    for (int i = 0; i < 4; i++) {
        const int row = ty + i * 8;
        t[row][tx] = src[(size_t)(gy + row) * 3072 + gx + tx];
    }
    __syncthreads();
    #pragma unroll
    for (int i = 0; i < 4; i++) {
        const int nr = ty + i * 8;
        dst[(size_t)(gx + nr) * 512 + gy + tx] = t[tx][nr];
    }
}

// ------------- transpose+cast weight: src fp32 [Kd][N] (row stride ld) -> dst bf16 [N][Kd] -----
__global__ __launch_bounds__(256) void wt_k(
    const float* __restrict__ src, int ld, int Kd, ushort_t* __restrict__ dst)
{
    __shared__ float t[32][33];
    const int tx = threadIdx.x & 31, ty = threadIdx.x >> 5;
    const int gx = blockIdx.x * 32;
    const int gy = blockIdx.y * 32;
    #pragma unroll
    for (int i = 0; i < 4; i++) {
        const int row = ty + i * 8;
        t[row][tx] = src[(size_t)(gy + row) * ld + gx + tx];
    }
    __syncthreads();
    #pragma unroll
    for (int i = 0; i < 4; i++) {
        const int nr = ty + i * 8;
        dst[(size_t)(gx + nr) * Kd + gy + tx] = f2bf(t[tx][nr]);
    }
}

// ------------- fused shift-predictor + TSM shift (dual fp32/bf16 out) --------------------------
__global__ __launch_bounds__(256) void predshift_k(
    const float* __restrict__ x, const float* __restrict__ pred_w,
    const float* __restrict__ pred_b, float* __restrict__ h, ushort_t* __restrict__ hb)
{
    const int row = blockIdx.x, tid = threadIdx.x;
    const size_t base = (size_t)row * Dz;
    float s = 0.f;
    #pragma unroll
    for (int i = 0; i < 4; i++) {
        int c = tid + i * 256;
        s += x[base + c] * pred_w[c];
    }
    __shared__ float red[256];
    __shared__ int sns;
    red[tid] = s; __syncthreads();
    for (int off = 128; off > 0; off >>= 1) {
        if (tid < off) red[tid] += red[tid + off];
        __syncthreads();
    }
    if (tid == 0) {
        float sg = 1.f / (1.f + expf(-(red[0] + pred_b[0])));
        sns = (int)(sg * (float)(Dz / 2));
    }
    __syncthreads();
    const int sn = sns;
    const int t = row & (Tz - 1);
    #pragma unroll
    for (int i = 0; i < 4; i++) {
        const int c = tid + i * 256;
        const size_t idx = base + c;
        float v;
        if (c < sn)          v = (t > 0)      ? x[idx - Dz] : 0.f;
        else if (c < 2 * sn) v = (t < Tz - 1) ? x[idx + Dz] : 0.f;
        else                 v = x[idx];
        h[idx] = v; hb[idx] = f2bf(v);
    }
}

// ------------- h = LN(h + r); dual write h fp32 + hb bf16 --------------------------------------
__global__ __launch_bounds__(256) void addln_k(
    float* __restrict__ h, ushort_t* __restrict__ hb,
    const float* __restrict__ r, int ldr,
    const float* __restrict__ g, const float* __restrict__ b)
{
    const int row = blockIdx.x, tid = threadIdx.x;
    const size_t base = (size_t)row * Dz;
    const size_t baser = (size_t)row * ldr;
    float x[4]; float s = 0.f, sq = 0.f;
    #pragma unroll
    for (int i = 0; i < 4; i++) {
        x[i] = h[base + tid + i * 256] + r[baser + tid + i * 256];
        s += x[i]; sq += x[i] * x[i];
    }
    __shared__ float rs[256], rq[256];
    rs[tid] = s; rq[tid] = sq; __syncthreads();
    for (int off = 128; off > 0; off >>= 1) {
        if (tid < off) { rs[tid] += rs[tid + off]; rq[tid] += rq[tid + off]; }
        __syncthreads();
    }
    float mean = rs[0] * (1.f / Dz);
    float var = rq[0] * (1.f / Dz) - mean * mean;
    float inv = rsqrtf(var + EPSz);
    #pragma unroll
    for (int i = 0; i < 4; i++) {
        int c = tid + i * 256;
        float y = (x[i] - mean) * inv * g[c] + b[c];
        h[base + c] = y; hb[base + c] = f2bf(y);
    }
}

// ------------- rowdot: out[row] = dot(in[row,:512], w) + b -------------------------------------
__global__ __launch_bounds__(256) void rowdot_k(
    const float* __restrict__ in, const float* __restrict__ w,
    const float* __restrict__ bptr, float* __restrict__ outf)
{
    const int row = blockIdx.x, tid = threadIdx.x;
    const float* r = in + (size_t)row * Pz;
    float s = 0.f;
    #pragma unroll
    for (int c = tid; c < Pz; c += 256) s += r[c] * w[c];
    __shared__ float red[256];
    red[tid] = s; __syncthreads();
    for (int off = 128; off > 0; off >>= 1) {
        if (tid < off) red[tid] += red[tid + off];
        __syncthreads();
    }
    if (tid == 0) outf[row] = red[0] + bptr[0];
}

// ------------- top-k (7 of 512) per (chunk-local) batch row ------------------------------------
__global__ __launch_bounds__(256) void topk_k(const float* __restrict__ scores, int* __restrict__ idx)
{
    const int b = blockIdx.x, tid = threadIdx.x;
    __shared__ float sv[Tz];
    __shared__ float rv[256]; __shared__ int ri[256];
    sv[tid] = scores[b * Tz + tid];
    sv[tid + 256] = scores[b * Tz + tid + 256];
    __syncthreads();
    for (int it = 0; it < TOPKz; it++) {
        float v0 = sv[tid]; int i0 = tid;
        float v1 = sv[tid + 256];
        if (v1 > v0) { v0 = v1; i0 = tid + 256; }
        rv[tid] = v0; ri[tid] = i0; __syncthreads();
        for (int off = 128; off > 0; off >>= 1) {
            if (tid < off) {
                if (rv[tid + off] > rv[tid] ||
                    (rv[tid + off] == rv[tid] && ri[tid + off] < ri[tid])) {
                    rv[tid] = rv[tid + off]; ri[tid] = ri[tid + off];
                }
            }
            __syncthreads();
        }
        if (tid == 0) { idx[b * TOPKz + it] = ri[0]; sv[ri[0]] = -INFINITY; }
        __syncthreads();
    }
}

// ------------- agg = mean of top-k rows of shared ---------------------------------------------
__global__ __launch_bounds__(256) void agg_k(
    const float* __restrict__ sh, const int* __restrict__ idx, float* __restrict__ agg)
{
    const int b = blockIdx.x, tid = threadIdx.x;
    for (int p = tid; p < Pz; p += 256) {
        float s = 0.f;
        #pragma unroll
        for (int j = 0; j < TOPKz; j++) {
            int t = idx[b * TOPKz + j];
            s += sh[((size_t)b * Tz + t) * Pz + p];
        }
        agg[b * Pz + p] = s * (1.f / TOPKz);
    }
}

// ------------- fused classifier: c1 -> logits -> softmax -> cat_emb -> cross-q -----------------
__global__ __launch_bounds__(256) void cls_k(
    const float* __restrict__ agg,
    const float* __restrict__ cc_w1, const float* __restrict__ cc_b1,
    const float* __restrict__ g2, const float* __restrict__ b2,
    const float* __restrict__ m2, const float* __restrict__ v2,
    const float* __restrict__ cc_w2, const float* __restrict__ cc_b2,
    const float* __restrict__ ce,
    const float* __restrict__ ca_wqkv, const float* __restrict__ ca_bqkv,
    float* __restrict__ logits_out, float* __restrict__ qx)
{
    const int b = blockIdx.x, tid = threadIdx.x;
    __shared__ float ag[Pz], c1s[256], sm[16], cemb[256];
    ag[tid] = agg[b * Pz + tid];
    ag[tid + 256] = agg[b * Pz + tid + 256];
    __syncthreads();
    float s = 0.f;
    for (int p = 0; p < Pz; p++) s += ag[p] * cc_w1[p * 256 + tid];
    s += cc_b1[tid];
    s = (s - m2[tid]) * rsqrtf(v2[tid] + EPSz) * g2[tid] + b2[tid];
    s = fmaxf(s, 0.f);
    c1s[tid] = s;
    __syncthreads();
    if (tid < KC) {
        float l = 0.f;
        for (int e = 0; e < 256; e++) l += c1s[e] * cc_w2[e * KC + tid];
        l += cc_b2[tid];
        sm[tid] = l;
        logits_out[b * KC + tid] = l;
    }
    __syncthreads();
    if (tid == 0) {
        float mx = sm[0];
        for (int k = 1; k < KC; k++) mx = fmaxf(mx, sm[k]);
        float su = 0.f;
        for (int k = 0; k < KC; k++) { sm[k] = expf(sm[k] - mx); su += sm[k]; }
        float inv = 1.f / su;
        for (int k = 0; k < KC; k++) sm[k] *= inv;
    }
    __syncthreads();
    float cesum = 0.f;
    #pragma unroll
    for (int k = 0; k < KC; k++) cesum += sm[k] * ce[k * 256 + tid];
    cemb[tid] = cesum; __syncthreads();
    float q = 0.f;
    for (int i = 0; i < 256; i++) q += cemb[i] * ca_wqkv[i * 768 + tid];
    qx[b * 256 + tid] = q + ca_bqkv[tid];
}

// ------------- cross-attention (Tq=1) on combined kv[R,512] ------------------------------------
__global__ __launch_bounds__(256) void xattn_k(
    const float* __restrict__ qx, const float* __restrict__ kv, float* __restrict__ ctx)
{
    const int b = blockIdx.x, tid = threadIdx.x;
    __shared__ float q4[256];
    __shared__ float sc[NHz][Tz];
    q4[tid] = qx[b * 256 + tid];
    __syncthreads();
    for (int si = tid; si < NHz * Tz; si += 256) {
        int hh = si >> 9, t = si & (Tz - 1);
        const float* kr = kv + ((size_t)b * Tz + t) * 512 + hh * 64;
        const float* qr = q4 + hh * 64;
        float s = 0.f;
        #pragma unroll 8
        for (int d = 0; d < 64; d++) s += qr[d] * kr[d];
        sc[hh][t] = s * 0.125f;
    }
    __syncthreads();
    const int hh = tid >> 6, lane = tid & 63;
    float mx = -INFINITY;
    for (int t = lane; t < Tz; t += 64) mx = fmaxf(mx, sc[hh][t]);
    for (int off = 32; off > 0; off >>= 1) mx = fmaxf(mx, __shfl_xor(mx, off));
    float su = 0.f;
    for (int t = lane; t < Tz; t += 64) { float e = expf(sc[hh][t] - mx); sc[hh][t] = e; su += e; }
    for (int off = 32; off > 0; off >>= 1) su += __shfl_xor(su, off);
    float inv = 1.f / su;
    __syncthreads();
    float acc = 0.f;
    for (int t = 0; t < Tz; t++) acc += sc[hh][t] * kv[((size_t)b * Tz + t) * 512 + 256 + tid];
    ctx[b * 256 + tid] = acc * inv;
}

// ------------- ctx2 = ctx @ ca_wo + ca_bo ------------------------------------------------------
__global__ __launch_bounds__(256) void ctx2_k(
    const float* __restrict__ ctx, const float* __restrict__ ca_wo,
    const float* __restrict__ ca_bo, float* __restrict__ ctx2)
{
    const int b = blockIdx.x, tid = threadIdx.x;
    __shared__ float c[256];
    c[tid] = ctx[b * 256 + tid]; __syncthreads();
    float s = 0.f;
    for (int i = 0; i < 256; i++) s += c[i] * ca_wo[i * 256 + tid];
    ctx2[b * 256 + tid] = s + ca_bo[tid];
}

// ------------- fb = bf16(proj + ctx2) (broadcast over T) ---------------------------------------
__global__ __launch_bounds__(256) void addctx_k(
    const float* __restrict__ proj, const float* __restrict__ ctx2, ushort_t* __restrict__ fb)
{
    size_t idx = (size_t)blockIdx.x * 256 + threadIdx.x;   // over R*E
    int e = (int)(idx & 255);
    int b = (int)(idx >> 17);                              // T*E = 2^17
    fb[idx] = f2bf(proj[idx] + ctx2[b * 256 + e]);
}

// ==============================================================================================
extern "C" void kernel_launch(void* const* d_in, const int* in_sizes, int n_in,
                              void* d_out, int out_size, void* d_ws, size_t ws_size,
                              hipStream_t stream)
{
    const float* x       = (const float*)d_in[0];
    const float* pred_w  = (const float*)d_in[1];
    const float* pred_b  = (const float*)d_in[2];
    const float* t_wqkv  = (const float*)d_in[3];
    const float* t_bqkv  = (const float*)d_in[4];
    const float* t_wo    = (const float*)d_in[5];
    const float* t_bo    = (const float*)d_in[6];
    const float* t_ln1g  = (const float*)d_in[7];
    const float* t_ln1b  = (const float*)d_in[8];
    const float* t_w1    = (const float*)d_in[9];
    const float* t_b1    = (const float*)d_in[10];
    const float* t_w2    = (const float*)d_in[11];
    const float* t_b2    = (const float*)d_in[12];
    const float* t_ln2g  = (const float*)d_in[13];
    const float* t_ln2b  = (const float*)d_in[14];
    const float* sb_w    = (const float*)d_in[15];
    const float* sb_b    = (const float*)d_in[16];
    const float* bn1_g   = (const float*)d_in[17];
    const float* bn1_b   = (const float*)d_in[18];
    const float* bn1_m   = (const float*)d_in[19];
    const float* bn1_v   = (const float*)d_in[20];
    const float* dt_w    = (const float*)d_in[21];
    const float* dt_b    = (const float*)d_in[22];
    const float* cc_w1   = (const float*)d_in[23];
    const float* cc_b1   = (const float*)d_in[24];
    const float* bn2_g   = (const float*)d_in[25];
    const float* bn2_b   = (const float*)d_in[26];
    const float* bn2_m   = (const float*)d_in[27];
    const float* bn2_v   = (const float*)d_in[28];
    const float* cc_w2   = (const float*)d_in[29];
    const float* cc_b2   = (const float*)d_in[30];
    const float* ce      = (const float*)d_in[31];
    const float* kp_w    = (const float*)d_in[32];
    const float* kp_b    = (const float*)d_in[33];
    const float* ca_wqkv = (const float*)d_in[34];
    const float* ca_bqkv = (const float*)d_in[35];
    const float* ca_wo   = (const float*)d_in[36];
    const float* ca_bo   = (const float*)d_in[37];
    const float* fp_w    = (const float*)d_in[38];
    const float* fp_b    = (const float*)d_in[39];
    const float* df_w    = (const float*)d_in[40];
    const float* df_b    = (const float*)d_in[41];

    float* out = (float*)d_out;

    char* wp = (char*)d_ws;
    auto alloc = [&](size_t bytes) -> char* {
        char* r = wp; wp += (bytes + 255) & ~(size_t)255; return r;
    };
    float* scores  = (float*)alloc(BT * 4);
    int*   tkidx   = (int*)alloc(256 * 4);
    float* aggbuf  = (float*)alloc((size_t)Bz * Pz * 4);
    float* qxbuf   = (float*)alloc((size_t)Bz * Ez * 4);
    float* ctxbuf  = (float*)alloc((size_t)Bz * Ez * 4);
    float* ctx2buf = (float*)alloc((size_t)Bz * Ez * 4);

    const size_t WT_TOTAL = 2*(size_t)3072*1024 + 2*(size_t)1024*1024 + 2*(size_t)2048*1024
                          + 2*(size_t)1024*2048 + (size_t)512*1024 + (size_t)256*512
                          + 2*(size_t)256*256 + (size_t)1024*256;
    ushort_t* wtb = (ushort_t*)alloc(WT_TOTAL * 2);
    size_t woff = 0;
    auto nxt = [&](size_t n) -> ushort_t* { ushort_t* r = wtb + woff; woff += n; return r; };
    ushort_t* qkvT[2] = { nxt((size_t)3072*1024), nxt((size_t)3072*1024) };
    ushort_t* woT[2]  = { nxt((size_t)1024*1024), nxt((size_t)1024*1024) };
    ushort_t* w1T[2]  = { nxt((size_t)2048*1024), nxt((size_t)2048*1024) };
    ushort_t* w2T[2]  = { nxt((size_t)1024*2048), nxt((size_t)1024*2048) };
    ushort_t* sbT  = nxt((size_t)512*1024);
    ushort_t* kpT  = nxt((size_t)256*512);
    ushort_t* kvT  = nxt((size_t)512*256);   // combined cross k|v weight [512][256]
    ushort_t* fpT  = nxt((size_t)1024*256);

    // per-row bytes: h 4096 + hb 2048 + qkvb 6144 + scr 8192 + Pb 4096 + Vt 2048 = 26624
    size_t fixedB = (size_t)(wp - (char*)d_ws);
    int Bc = Bz;
    while (Bc > 1 && fixedB + (size_t)Bc * Tz * 26624 + 1048576 > ws_size) Bc >>= 1;
    const int Rmax = Bc * Tz;
    float*    h    = (float*)alloc((size_t)Rmax * 1024 * 4);
    ushort_t* hb   = (ushort_t*)alloc((size_t)Rmax * 1024 * 2);
    ushort_t* qkvb = (ushort_t*)alloc((size_t)Rmax * 3072 * 2);
    float*    scr  = (float*)alloc((size_t)Rmax * 2048 * 4);   // S / wo-out / ff2-out / tail f32
    ushort_t* Pb   = (ushort_t*)alloc((size_t)Rmax * 2048 * 2);
    ushort_t* Vt   = (ushort_t*)alloc((size_t)Rmax * 1024 * 2);

    // ---- one-time weight transpose+cast ----
    for (int l = 0; l < Lz; l++) {
        wt_k<<<dim3(3072/32, 1024/32), 256, 0, stream>>>(t_wqkv + (size_t)l*1024*3072, 3072, 1024, qkvT[l]);
        wt_k<<<dim3(1024/32, 1024/32), 256, 0, stream>>>(t_wo   + (size_t)l*1024*1024, 1024, 1024, woT[l]);
        wt_k<<<dim3(2048/32, 1024/32), 256, 0, stream>>>(t_w1   + (size_t)l*1024*2048, 2048, 1024, w1T[l]);
        wt_k<<<dim3(1024/32, 2048/32), 256, 0, stream>>>(t_w2   + (size_t)l*2048*1024, 1024, 2048, w2T[l]);
    }
    wt_k<<<dim3(512/32, 1024/32), 256, 0, stream>>>(sb_w, 512, 1024, sbT);
    wt_k<<<dim3(256/32,  512/32), 256, 0, stream>>>(kp_w, 256, 512, kpT);
    wt_k<<<dim3(256/32,  256/32), 256, 0, stream>>>(ca_wqkv + Ez,     768, 256, kvT);
    wt_k<<<dim3(256/32,  256/32), 256, 0, stream>>>(ca_wqkv + 2*Ez,   768, 256, kvT + (size_t)256*256);
    wt_k<<<dim3(1024/32, 256/32), 256, 0, stream>>>(fp_w, 1024, 256, fpT);

    for (int b0 = 0; b0 < Bz; b0 += Bc) {
        const int R = Bc * Tz;
        const float* xc = x + (size_t)b0 * Tz * Dz;

        auto MG = [&](const ushort_t* Ain, int lda, const ushort_t* Wt_, const float* bias,
                      float* Cf, ushort_t* Ch, int ldc, int N, int Kd, int epi,
                      const float* g = nullptr, const float* bb = nullptr,
                      const float* m = nullptr, const float* v = nullptr) {
            mgemm_k<<<dim3(N/128, R/128), 256, 0, stream>>>(
                Ain, lda, Wt_, bias, Cf, Ch, ldc, Kd, epi, g, bb, m, v);
        };
        auto MG8 = [&](const ushort_t* Ain, int lda, const ushort_t* Wt_, const float* bias,
                       float* Cf, ushort_t* Ch, int ldc, int N, int Kd, int epi) {
            mgemm8_k<<<dim3(N/256, R/256), 512, 0, stream>>>(
                Ain, lda, Wt_, bias, Cf, Ch, ldc, Kd, epi,
                nullptr, nullptr, nullptr, nullptr);
        };

        // 1. fused shift-predictor + TSM -> h, hb
        predshift_k<<<R, 256, 0, stream>>>(xc, pred_w, pred_b, h, hb);

        // 2. transformer layers
        for (int l = 0; l < Lz; l++) {
            MG8(hb, 1024, qkvT[l], t_bqkv + (size_t)l*3072, nullptr, qkvb, 3072, 3072, 1024, 0);
            vtb_k<<<dim3(8, 16, Bc * 4), 256, 0, stream>>>(qkvb, Vt);
            bgemm_k<<<dim3(4, 4, Bc * 4), 256, 0, stream>>>(
                qkvb, 3072, (size_t)512 * 3072, 256,
                qkvb + 1024, 3072, (size_t)512 * 3072, 256,
                scr, nullptr, 512, (size_t)4 * 512 * 512, 512 * 512, 256);
            softmax_k<<<R, 256, 0, stream>>>(scr, Pb);
            bgemm_k<<<dim3(2, 4, Bc * 4), 256, 0, stream>>>(
                Pb, 512, (size_t)4 * 512 * 512, 512 * 512,
                Vt, 512, (size_t)4 * 256 * 512, 256 * 512,
                nullptr, qkvb, 3072, (size_t)512 * 3072, 256, 512);
            MG8(qkvb, 3072, woT[l], t_bo + (size_t)l*1024, scr, nullptr, 1024, 1024, 1024, 0);
            addln_k<<<R, 256, 0, stream>>>(h, hb, scr, 1024,
                                           t_ln1g + (size_t)l*Dz, t_ln1b + (size_t)l*Dz);
            MG8(hb, 1024, w1T[l], t_b1 + (size_t)l*FFz, nullptr, qkvb, 2048, 2048, 1024, 1);
            MG8(qkvb, 2048, w2T[l], t_b2 + (size_t)l*Dz, scr, nullptr, 1024, 1024, 2048, 0);
            addln_k<<<R, 256, 0, stream>>>(h, hb, scr, 1024,
                                           t_ln2g + (size_t)l*Dz, t_ln2b + (size_t)l*Dz);
        }

        // tail buffers sublet scr (f32) and Pb (bf16)
        float*    shared  = scr;                       // [R,512]
        float*    proj    = scr + (size_t)R * 512;     // [R,256]
        float*    kvb     = scr + (size_t)R * 768;     // [R,512] combined k|v
        float*    fin     = scr + (size_t)R * 1280;    // [R,512]
        ushort_t* sharedb = Pb;                        // [R,512]
        ushort_t* projb   = Pb + (size_t)R * 512;      // [R,256]
        ushort_t* fb      = Pb + (size_t)R * 768;      // [R,256]
        ushort_t* fpb     = qkvb;                      // [R,1024]

        // 3. shared = relu(BN1(h @ sb_w + sb_b))  (dual out)
        MG(hb, 1024, sbT, sb_b, shared, sharedb, 512, 512, 1024, 2, bn1_g, bn1_b, bn1_m, bn1_v);
        // 4. scores, top-k, agg, classifier
        rowdot_k<<<R, 256, 0, stream>>>(shared, dt_w, dt_b, scores + (size_t)b0 * Tz);
        topk_k<<<Bc, 256, 0, stream>>>(scores + (size_t)b0 * Tz, tkidx);
        agg_k<<<Bc, 256, 0, stream>>>(shared, tkidx, aggbuf);
        cls_k<<<Bc, 256, 0, stream>>>(aggbuf, cc_w1, cc_b1, bn2_g, bn2_b, bn2_m, bn2_v,
                                      cc_w2, cc_b2, ce, ca_wqkv, ca_bqkv,
                                      out + BT + (size_t)b0 * KC, qxbuf);
        // 5. proj (dual), combined cross k|v
        MG(sharedb, 512, kpT, kp_b, proj, projb, 256, 256, 512, 0);
        MG(projb, 256, kvT, ca_bqkv + Ez, kvb, nullptr, 512, 512, 256, 0);
        // 6. cross attention + final fuse
        xattn_k<<<Bc, 256, 0, stream>>>(qxbuf, kvb, ctxbuf);
        ctx2_k<<<Bc, 256, 0, stream>>>(ctxbuf, ca_wo, ca_bo, ctx2buf);
        addctx_k<<<(R * Ez) / 256, 256, 0, stream>>>(proj, ctx2buf, fb);
        // 7. fp_out (bf16) -> fin (BN+relu fp32) -> seg
        MG(fb, 256, fpT, fp_b, nullptr, fpb, 1024, 1024, 256, 0);
        MG(fpb, 1024, sbT, sb_b, fin, nullptr, 512, 512, 1024, 2, bn1_g, bn1_b, bn1_m, bn1_v);
        rowdot_k<<<R, 256, 0, stream>>>(fin, df_w, df_b, out + (size_t)b0 * Tz);
    }
}

// Round 7
// 2064.727 us; speedup vs baseline: 1.0275x; 1.0275x over previous
//
#include <hip/hip_runtime.h>
#include <math.h>

#define Bz 32
#define Tz 512
#define Dz 1024
#define Pz 512
#define Ez 256
#define KC 14
#define NHz 4
#define Lz 2
#define FFz 2048
#define TOPKz 7
#define EPSz 1e-5f
#define BT (Bz*Tz)

typedef unsigned short ushort_t;
typedef __attribute__((ext_vector_type(8))) short short8;
typedef __attribute__((ext_vector_type(4))) float f32x4;

__device__ __forceinline__ ushort_t f2bf(float f) {
    union { float f; unsigned int u; } x; x.f = f;
    unsigned int r = x.u + 0x7fffu + ((x.u >> 16) & 1u);   // RNE (finite inputs)
    return (ushort_t)(r >> 16);
}

// =================== 8-phase 256x256 bf16 MFMA GEMM (m201-style, plain HIP) ===================
// C = A[M,K]bf16 @ W^T[N,K]bf16. 8 waves (2Mx4N), BK=64, 128KB LDS dbuf, counted vmcnt,
// setprio around MFMA clusters. Swizzle (rule #21, both-sides): LDS slot(row,chunk g) holds
// global chunk g ^ (row&7); staged via inverse-permuted global source col, read via byte XOR.
__global__ __launch_bounds__(512, 2) void mgemm8_k(
    const ushort_t* __restrict__ A, int lda,
    const ushort_t* __restrict__ Wt,                  // [N][Kd]
    const float* __restrict__ bias,
    float* __restrict__ Cf, ushort_t* __restrict__ Ch, int ldc,
    int Kd, int epi,
    const float* __restrict__ bng, const float* __restrict__ bnb,
    const float* __restrict__ bnm, const float* __restrict__ bnv)
{
    __shared__ __align__(16) ushort_t AsB[2][256 * 64];
    __shared__ __align__(16) ushort_t BsB[2][256 * 64];
    const int tid = threadIdx.x;
    const int lane = tid & 63, w = tid >> 6;          // 8 waves
    const int wr = w >> 2, wc = w & 3;                // 2 x 4
    const int row0 = blockIdx.y * 256, col0 = blockIdx.x * 256;
    const int T = Kd >> 6;                            // K-tiles of 64

    // staging: one global_load_lds covers 8 rows x 128B. lane>>3 = row offset, lane&7 = slot.
    // source element col = ((lane&7) ^ (lane>>3)) * 8  -> LDS slot j of row r holds chunk j^(r&7).
    const int colE = (((lane & 7) ^ (lane >> 3)) << 3);

    auto STAGE_A = [&](int k, int hf) {               // hf: 0 -> rows {0-63,128-191}, 1 -> +64
        const int buf = k & 1;
        #pragma unroll
        for (int i = 0; i < 2; i++) {
            const int rbu = hf * 64 + i * 128 + w * 8;          // wave-uniform row base
            const int row = rbu + (lane >> 3);
            const ushort_t* g = A + (size_t)(row0 + row) * lda + k * 64 + colE;
            ushort_t* l = AsB[buf] + rbu * 64;
            __builtin_amdgcn_global_load_lds(
                (const __attribute__((address_space(1))) unsigned int*)g,
                (__attribute__((address_space(3))) unsigned int*)l, 16, 0, 0);
        }
    };
    auto STAGE_B = [&](int k, int hf) {               // hf: 0 -> rows {0-31 mod 64 pattern}, 1 -> +32
        const int buf = k & 1;
        #pragma unroll
        for (int i = 0; i < 2; i++) {
            const int rbu = i * 128 + (w >> 2) * 64 + (w & 3) * 8 + hf * 32;
            const int row = rbu + (lane >> 3);
            const ushort_t* g = Wt + (size_t)(col0 + row) * Kd + k * 64 + colE;
            ushort_t* l = BsB[buf] + rbu * 64;
            __builtin_amdgcn_global_load_lds(
                (const __attribute__((address_space(1))) unsigned int*)g,
                (__attribute__((address_space(3))) unsigned int*)l, 16, 0, 0);
        }
    };

    // prologue: stage tiles 0 and 1 fully; keep tile1 (8 loads) in flight past the wait
    STAGE_A(0, 0); STAGE_A(0, 1); STAGE_B(0, 0); STAGE_B(0, 1);
    STAGE_A(1, 0); STAGE_A(1, 1); STAGE_B(1, 0); STAGE_B(1, 1);
    asm volatile("s_waitcnt vmcnt(8)" ::: "memory");
    __builtin_amdgcn_s_barrier();

    f32x4 acc[8][4];
    const f32x4 zr = {0.f, 0.f, 0.f, 0.f};
    #pragma unroll
    for (int m = 0; m < 8; m++)
        #pragma unroll
        for (int n = 0; n < 4; n++) acc[m][n] = zr;

    // read-side swizzle: byte col ^= (row&7)<<4 ; row&7 == lane&7 (all other row terms %16==0)
    const int cbband = (lane & 7) << 4;
    const int cbase = (lane >> 4) * 16;               // byte col of fragment within 64B k-slice

    for (int t = 0; t < T; t++) {
        const ushort_t* Ab = AsB[t & 1];
        const ushort_t* Bb = BsB[t & 1];
        short8 af[4][2], bf0[2][2], bf1[2][2];

        auto LDA = [&](int mh) {
            #pragma unroll
            for (int m2 = 0; m2 < 4; m2++) {
                const int r = wr * 128 + mh * 64 + m2 * 16 + (lane & 15);
                const char* rp = (const char*)Ab + (size_t)r * 128;
                #pragma unroll
                for (int ks = 0; ks < 2; ks++)
                    af[m2][ks] = *(const short8*)(rp + ((ks * 64 + cbase) ^ cbband));
            }
        };
        auto LDB = [&](short8 (*dst)[2], int nh) {
            #pragma unroll
            for (int n2 = 0; n2 < 2; n2++) {
                const int r = wc * 64 + nh * 32 + n2 * 16 + (lane & 15);
                const char* rp = (const char*)Bb + (size_t)r * 128;
                #pragma unroll
                for (int ks = 0; ks < 2; ks++)
                    dst[n2][ks] = *(const short8*)(rp + ((ks * 64 + cbase) ^ cbband));
            }
        };

        // ---- phase 0: quadrant (mh=0, nh=0) ----
        LDA(0); LDB(bf0, 0);
        if (t >= 1 && t + 1 < T) STAGE_A(t + 1, 1);
        __builtin_amdgcn_s_barrier();
        __builtin_amdgcn_s_setprio(1);
        #pragma unroll
        for (int m2 = 0; m2 < 4; m2++)
            #pragma unroll
            for (int n2 = 0; n2 < 2; n2++)
                #pragma unroll
                for (int ks = 0; ks < 2; ks++)
                    acc[m2][n2] = __builtin_amdgcn_mfma_f32_16x16x32_bf16(af[m2][ks], bf0[n2][ks], acc[m2][n2], 0, 0, 0);
        __builtin_amdgcn_s_setprio(0);
        __builtin_amdgcn_s_barrier();

        // ---- phase 1: (mh=0, nh=1) ----
        LDB(bf1, 1);
        if (t >= 1 && t + 1 < T) STAGE_B(t + 1, 1);
        __builtin_amdgcn_s_barrier();
        __builtin_amdgcn_s_setprio(1);
        #pragma unroll
        for (int m2 = 0; m2 < 4; m2++)
            #pragma unroll
            for (int n2 = 0; n2 < 2; n2++)
                #pragma unroll
                for (int ks = 0; ks < 2; ks++)
                    acc[m2][2 + n2] = __builtin_amdgcn_mfma_f32_16x16x32_bf16(af[m2][ks], bf1[n2][ks], acc[m2][2 + n2], 0, 0, 0);
        __builtin_amdgcn_s_setprio(0);
        __builtin_amdgcn_s_barrier();

        // ---- phase 2: (mh=1, nh=0) --- A-h0 rows of buf (t&1) free after phase 0 ----
        LDA(1);
        if (t + 2 < T) STAGE_A(t + 2, 0);
        __builtin_amdgcn_s_barrier();
        __builtin_amdgcn_s_setprio(1);
        #pragma unroll
        for (int m2 = 0; m2 < 4; m2++)
            #pragma unroll
            for (int n2 = 0; n2 < 2; n2++)
                #pragma unroll
                for (int ks = 0; ks < 2; ks++)
                    acc[4 + m2][n2] = __builtin_amdgcn_mfma_f32_16x16x32_bf16(af[m2][ks], bf0[n2][ks], acc[4 + m2][n2], 0, 0, 0);
        __builtin_amdgcn_s_setprio(0);
        __builtin_amdgcn_s_barrier();

        // ---- phase 3: (mh=1, nh=1) ----
        if (t + 2 < T) STAGE_B(t + 2, 0);
        __builtin_amdgcn_s_barrier();
        __builtin_amdgcn_s_setprio(1);
        #pragma unroll
        for (int m2 = 0; m2 < 4; m2++)
            #pragma unroll
            for (int n2 = 0; n2 < 2; n2++)
                #pragma unroll
                for (int ks = 0; ks < 2; ks++)
                    acc[4 + m2][2 + n2] = __builtin_amdgcn_mfma_f32_16x16x32_bf16(af[m2][ks], bf1[n2][ks], acc[4 + m2][2 + n2], 0, 0, 0);
        __builtin_amdgcn_s_setprio(0);
        // boundary: tile t+1 must be resident; allowed in flight = t+2's staged 4 loads
        if (t + 2 < T) { asm volatile("s_waitcnt vmcnt(4)" ::: "memory"); }
        else           { asm volatile("s_waitcnt vmcnt(0)" ::: "memory"); }
        __builtin_amdgcn_s_barrier();
    }

    // ---- epilogue: bias / BN / relu, dual fp32+bf16 out ----
    #pragma unroll
    for (int ni = 0; ni < 4; ni++) {
        const int ccol = col0 + wc * 64 + ni * 16 + (lane & 15);
        const float bb = bias[ccol];
        float bsc = 1.f, bsh = 0.f;
        if (epi == 2) {
            bsc = rsqrtf(bnv[ccol] + EPSz) * bng[ccol];
            bsh = bnb[ccol] - bnm[ccol] * bsc;
        }
        #pragma unroll
        for (int mi = 0; mi < 8; mi++) {
            #pragma unroll
            for (int r = 0; r < 4; r++) {
                const int crow = row0 + wr * 128 + mi * 16 + (lane >> 4) * 4 + r;
                float y = acc[mi][ni][r] + bb;
                if (epi == 2) y = y * bsc + bsh;
                if (epi >= 1) y = fmaxf(y, 0.f);
                if (Cf) Cf[(size_t)crow * ldc + ccol] = y;
                if (Ch) Ch[(size_t)crow * ldc + ccol] = f2bf(y);
            }
        }
    }
}

// ---------------- 128x128 bf16 MFMA GEMM (m97 structure) for small N / K -----------------------
__global__ __launch_bounds__(256) void mgemm_k(
    const ushort_t* __restrict__ A, int lda,
    const ushort_t* __restrict__ Wt,
    const float* __restrict__ bias,
    float* __restrict__ Cf, ushort_t* __restrict__ Ch, int ldc,
    int Kd, int epi,
    const float* __restrict__ bng, const float* __restrict__ bnb,
    const float* __restrict__ bnm, const float* __restrict__ bnv)
{
    __shared__ __align__(16) ushort_t As[128 * 32];
    __shared__ __align__(16) ushort_t Bs[128 * 32];
    const int tid = threadIdx.x;
    const int lane = tid & 63, wid = tid >> 6;
    const int row0 = blockIdx.y * 128, col0 = blockIdx.x * 128;
    const int wrow = (wid >> 1) * 64, wcol = (wid & 1) * 64;
    const int srow = (lane >> 2);
    const int skoff = (lane & 3) * 8;

    f32x4 acc[4][4];
    const f32x4 zr = {0.f, 0.f, 0.f, 0.f};
    #pragma unroll
    for (int m = 0; m < 4; m++)
        #pragma unroll
        for (int n = 0; n < 4; n++) acc[m][n] = zr;

    for (int k0 = 0; k0 < Kd; k0 += 32) {
        #pragma unroll
        for (int j = 0; j < 2; j++) {
            const int r = wid * 32 + j * 16;
            const ushort_t* ga = A + (size_t)(row0 + r + srow) * lda + k0 + skoff;
            __builtin_amdgcn_global_load_lds(
                (const __attribute__((address_space(1))) unsigned int*)ga,
                (__attribute__((address_space(3))) unsigned int*)(As + r * 32), 16, 0, 0);
            const ushort_t* gb = Wt + (size_t)(col0 + r + srow) * Kd + k0 + skoff;
            __builtin_amdgcn_global_load_lds(
                (const __attribute__((address_space(1))) unsigned int*)gb,
                (__attribute__((address_space(3))) unsigned int*)(Bs + r * 32), 16, 0, 0);
        }
        __syncthreads();
        short8 af[4], bf[4];
        #pragma unroll
        for (int m = 0; m < 4; m++)
            af[m] = *(const short8*)(As + (wrow + m * 16 + (lane & 15)) * 32 + (lane >> 4) * 8);
        #pragma unroll
        for (int n = 0; n < 4; n++)
            bf[n] = *(const short8*)(Bs + (wcol + n * 16 + (lane & 15)) * 32 + (lane >> 4) * 8);
        #pragma unroll
        for (int m = 0; m < 4; m++)
            #pragma unroll
            for (int n = 0; n < 4; n++)
                acc[m][n] = __builtin_amdgcn_mfma_f32_16x16x32_bf16(af[m], bf[n], acc[m][n], 0, 0, 0);
        __syncthreads();
    }

    #pragma unroll
    for (int n = 0; n < 4; n++) {
        const int ccol = col0 + wcol + n * 16 + (lane & 15);
        const float bb = bias[ccol];
        float bsc = 1.f, bsh = 0.f;
        if (epi == 2) {
            bsc = rsqrtf(bnv[ccol] + EPSz) * bng[ccol];
            bsh = bnb[ccol] - bnm[ccol] * bsc;
        }
        #pragma unroll
        for (int m = 0; m < 4; m++) {
            #pragma unroll
            for (int r = 0; r < 4; r++) {
                const int crow = row0 + wrow + m * 16 + (lane >> 4) * 4 + r;
                float y = acc[m][n][r] + bb;
                if (epi == 2) y = y * bsc + bsh;
                if (epi >= 1) y = fmaxf(y, 0.f);
                if (Cf) Cf[(size_t)crow * ldc + ccol] = y;
                if (Ch) Ch[(size_t)crow * ldc + ccol] = f2bf(y);
            }
        }
    }
}

// ---------------- batched bf16 MFMA GEMM over z=(batch,head): fp32 OR bf16 out -----------------
__global__ __launch_bounds__(256) void bgemm_k(
    const ushort_t* __restrict__ A0, int lda, size_t Abz, int Ahz,
    const ushort_t* __restrict__ W0, int ldw, size_t Wbz, int Whz,
    float* __restrict__ Cf0, ushort_t* __restrict__ Ch0, int ldc, size_t Cbz, int Chz, int Kd)
{
    const int z = blockIdx.z, bl = z >> 2, hh = z & 3;
    const ushort_t* A = A0 + (size_t)bl * Abz + (size_t)hh * Ahz;
    const ushort_t* W = W0 + (size_t)bl * Wbz + (size_t)hh * Whz;

    __shared__ __align__(16) ushort_t As[128 * 32];
    __shared__ __align__(16) ushort_t Bs[128 * 32];
    const int tid = threadIdx.x;
    const int lane = tid & 63, wid = tid >> 6;
    const int row0 = blockIdx.y * 128, col0 = blockIdx.x * 128;
    const int wrow = (wid >> 1) * 64, wcol = (wid & 1) * 64;
    const int srow = (lane >> 2);
    const int skoff = (lane & 3) * 8;

    f32x4 acc[4][4];
    const f32x4 zr = {0.f, 0.f, 0.f, 0.f};
    #pragma unroll
    for (int m = 0; m < 4; m++)
        #pragma unroll
        for (int n = 0; n < 4; n++) acc[m][n] = zr;

    for (int k0 = 0; k0 < Kd; k0 += 32) {
        #pragma unroll
        for (int j = 0; j < 2; j++) {
            const int r = wid * 32 + j * 16;
            const ushort_t* ga = A + (size_t)(row0 + r + srow) * lda + k0 + skoff;
            __builtin_amdgcn_global_load_lds(
                (const __attribute__((address_space(1))) unsigned int*)ga,
                (__attribute__((address_space(3))) unsigned int*)(As + r * 32), 16, 0, 0);
            const ushort_t* gb = W + (size_t)(col0 + r + srow) * ldw + k0 + skoff;
            __builtin_amdgcn_global_load_lds(
                (const __attribute__((address_space(1))) unsigned int*)gb,
                (__attribute__((address_space(3))) unsigned int*)(Bs + r * 32), 16, 0, 0);
        }
        __syncthreads();
        short8 af[4], bf[4];
        #pragma unroll
        for (int m = 0; m < 4; m++)
            af[m] = *(const short8*)(As + (wrow + m * 16 + (lane & 15)) * 32 + (lane >> 4) * 8);
        #pragma unroll
        for (int n = 0; n < 4; n++)
            bf[n] = *(const short8*)(Bs + (wcol + n * 16 + (lane & 15)) * 32 + (lane >> 4) * 8);
        #pragma unroll
        for (int m = 0; m < 4; m++)
            #pragma unroll
            for (int n = 0; n < 4; n++)
                acc[m][n] = __builtin_amdgcn_mfma_f32_16x16x32_bf16(af[m], bf[n], acc[m][n], 0, 0, 0);
        __syncthreads();
    }

    #pragma unroll
    for (int n = 0; n < 4; n++) {
        const int ccol = col0 + wcol + n * 16 + (lane & 15);
        #pragma unroll
        for (int m = 0; m < 4; m++) {
            #pragma unroll
            for (int r = 0; r < 4; r++) {
                const int crow = row0 + wrow + m * 16 + (lane >> 4) * 4 + r;
                const float y = acc[m][n][r];
                if (Cf0) (Cf0 + (size_t)bl * Cbz + (size_t)hh * Chz)[(size_t)crow * ldc + ccol] = y;
                if (Ch0) (Ch0 + (size_t)bl * Cbz + (size_t)hh * Chz)[(size_t)crow * ldc + ccol] = f2bf(y);
            }
        }
    }
}

// ------------- softmax over S rows (scale 1/16), write normalized P in bf16 --------------------
__global__ __launch_bounds__(256) void softmax_k(
    const float* __restrict__ S, ushort_t* __restrict__ P)
{
    const int row = blockIdx.x * 4 + (threadIdx.x >> 6);
    const int lane = threadIdx.x & 63;
    const float* sr = S + (size_t)row * 512 + lane * 8;
    const float4 a = *(const float4*)sr;
    const float4 b = *(const float4*)(sr + 4);
    float v[8] = {a.x, a.y, a.z, a.w, b.x, b.y, b.z, b.w};
    #pragma unroll
    for (int i = 0; i < 8; i++) v[i] *= 0.0625f;
    float m = v[0];
    #pragma unroll
    for (int i = 1; i < 8; i++) m = fmaxf(m, v[i]);
    #pragma unroll
    for (int off = 32; off > 0; off >>= 1) m = fmaxf(m, __shfl_xor(m, off));
    float s = 0.f;
    #pragma unroll
    for (int i = 0; i < 8; i++) { v[i] = expf(v[i] - m); s += v[i]; }
    #pragma unroll
    for (int off = 32; off > 0; off >>= 1) s += __shfl_xor(s, off);
    const float inv = 1.f / s;
    union { ushort_t h[8]; uint4 u; } pk;
    #pragma unroll
    for (int i = 0; i < 8; i++) pk.h[i] = f2bf(v[i] * inv);
    *(uint4*)(P + (size_t)row * 512 + lane * 8) = pk.u;
}

// ------------- z-batched bf16 transpose: V[kv][d] (qkvb v-slots) -> Vt[d][kv] ------------------
__global__ __launch_bounds__(256) void vtb_k(
    const ushort_t* __restrict__ qkvb, ushort_t* __restrict__ Vt)
{
    const int z = blockIdx.z, bl = z >> 2, hh = z & 3;
    const ushort_t* src = qkvb + (size_t)bl * 512 * 3072 + 2048 + hh * 256;
    ushort_t* dst = Vt + (size_t)z * 256 * 512;
    __shared__ ushort_t t[32][33];
    const int tx = threadIdx.x & 31, ty = threadIdx.x >> 5;
    const int gx = blockIdx.x * 32;   // d
    const int gy = blockIdx.y * 32;   // kv
    #pragma unroll
    for (int i = 0; i < 4; i++) {
        const int row = ty + i * 8;
        t[row][tx] = src[(size_t)(gy + row) * 3072 + gx + tx];
    }
    __syncthreads();
    #pragma unroll
    for (int i = 0; i < 4; i++) {
        const int nr = ty + i * 8;
        dst[(size_t)(gx + nr) * 512 + gy + tx] = t[tx][nr];
    }
}

// ------------- transpose+cast weight: src fp32 [Kd][N] (row stride ld) -> dst bf16 [N][Kd] -----
__global__ __launch_bounds__(256) void wt_k(
    const float* __restrict__ src, int ld, int Kd, ushort_t* __restrict__ dst)
{
    __shared__ float t[32][33];
    const int tx = threadIdx.x & 31, ty = threadIdx.x >> 5;
    const int gx = blockIdx.x * 32;
    const int gy = blockIdx.y * 32;
    #pragma unroll
    for (int i = 0; i < 4; i++) {
        const int row = ty + i * 8;
        t[row][tx] = src[(size_t)(gy + row) * ld + gx + tx];
    }
    __syncthreads();
    #pragma unroll
    for (int i = 0; i < 4; i++) {
        const int nr = ty + i * 8;
        dst[(size_t)(gx + nr) * Kd + gy + tx] = f2bf(t[tx][nr]);
    }
}

// ------------- fused shift-predictor + TSM shift (dual fp32/bf16 out) --------------------------
__global__ __launch_bounds__(256) void predshift_k(
    const float* __restrict__ x, const float* __restrict__ pred_w,
    const float* __restrict__ pred_b, float* __restrict__ h, ushort_t* __restrict__ hb)
{
    const int row = blockIdx.x, tid = threadIdx.x;
    const size_t base = (size_t)row * Dz;
    float s = 0.f;
    #pragma unroll
    for (int i = 0; i < 4; i++) {
        int c = tid + i * 256;
        s += x[base + c] * pred_w[c];
    }
    __shared__ float red[256];
    __shared__ int sns;
    red[tid] = s; __syncthreads();
    for (int off = 128; off > 0; off >>= 1) {
        if (tid < off) red[tid] += red[tid + off];
        __syncthreads();
    }
    if (tid == 0) {
        float sg = 1.f / (1.f + expf(-(red[0] + pred_b[0])));
        sns = (int)(sg * (float)(Dz / 2));
    }
    __syncthreads();
    const int sn = sns;
    const int t = row & (Tz - 1);
    #pragma unroll
    for (int i = 0; i < 4; i++) {
        const int c = tid + i * 256;
        const size_t idx = base + c;
        float v;
        if (c < sn)          v = (t > 0)      ? x[idx - Dz] : 0.f;
        else if (c < 2 * sn) v = (t < Tz - 1) ? x[idx + Dz] : 0.f;
        else                 v = x[idx];
        h[idx] = v; hb[idx] = f2bf(v);
    }
}

// ------------- h = LN(h + r); dual write h fp32 + hb bf16 --------------------------------------
__global__ __launch_bounds__(256) void addln_k(
    float* __restrict__ h, ushort_t* __restrict__ hb,
    const float* __restrict__ r, int ldr,
    const float* __restrict__ g, const float* __restrict__ b)
{
    const int row = blockIdx.x, tid = threadIdx.x;
    const size_t base = (size_t)row * Dz;
    const size_t baser = (size_t)row * ldr;
    float x[4]; float s = 0.f, sq = 0.f;
    #pragma unroll
    for (int i = 0; i < 4; i++) {
        x[i] = h[base + tid + i * 256] + r[baser + tid + i * 256];
        s += x[i]; sq += x[i] * x[i];
    }
    __shared__ float rs[256], rq[256];
    rs[tid] = s; rq[tid] = sq; __syncthreads();
    for (int off = 128; off > 0; off >>= 1) {
        if (tid < off) { rs[tid] += rs[tid + off]; rq[tid] += rq[tid + off]; }
        __syncthreads();
    }
    float mean = rs[0] * (1.f / Dz);
    float var = rq[0] * (1.f / Dz) - mean * mean;
    float inv = rsqrtf(var + EPSz);
    #pragma unroll
    for (int i = 0; i < 4; i++) {
        int c = tid + i * 256;
        float y = (x[i] - mean) * inv * g[c] + b[c];
        h[base + c] = y; hb[base + c] = f2bf(y);
    }
}

// ------------- rowdot: out[row] = dot(in[row,:512], w) + b -------------------------------------
__global__ __launch_bounds__(256) void rowdot_k(
    const float* __restrict__ in, const float* __restrict__ w,
    const float* __restrict__ bptr, float* __restrict__ outf)
{
    const int row = blockIdx.x, tid = threadIdx.x;
    const float* r = in + (size_t)row * Pz;
    float s = 0.f;
    #pragma unroll
    for (int c = tid; c < Pz; c += 256) s += r[c] * w[c];
    __shared__ float red[256];
    red[tid] = s; __syncthreads();
    for (int off = 128; off > 0; off >>= 1) {
        if (tid < off) red[tid] += red[tid + off];
        __syncthreads();
    }
    if (tid == 0) outf[row] = red[0] + bptr[0];
}

// ------------- top-k (7 of 512) per (chunk-local) batch row ------------------------------------
__global__ __launch_bounds__(256) void topk_k(const float* __restrict__ scores, int* __restrict__ idx)
{
    const int b = blockIdx.x, tid = threadIdx.x;
    __shared__ float sv[Tz];
    __shared__ float rv[256]; __shared__ int ri[256];
    sv[tid] = scores[b * Tz + tid];
    sv[tid + 256] = scores[b * Tz + tid + 256];
    __syncthreads();
    for (int it = 0; it < TOPKz; it++) {
        float v0 = sv[tid]; int i0 = tid;
        float v1 = sv[tid + 256];
        if (v1 > v0) { v0 = v1; i0 = tid + 256; }
        rv[tid] = v0; ri[tid] = i0; __syncthreads();
        for (int off = 128; off > 0; off >>= 1) {
            if (tid < off) {
                if (rv[tid + off] > rv[tid] ||
                    (rv[tid + off] == rv[tid] && ri[tid + off] < ri[tid])) {
                    rv[tid] = rv[tid + off]; ri[tid] = ri[tid + off];
                }
            }
            __syncthreads();
        }
        if (tid == 0) { idx[b * TOPKz + it] = ri[0]; sv[ri[0]] = -INFINITY; }
        __syncthreads();
    }
}

// ------------- agg = mean of top-k rows of shared ---------------------------------------------
__global__ __launch_bounds__(256) void agg_k(
    const float* __restrict__ sh, const int* __restrict__ idx, float* __restrict__ agg)
{
    const int b = blockIdx.x, tid = threadIdx.x;
    for (int p = tid; p < Pz; p += 256) {
        float s = 0.f;
        #pragma unroll
        for (int j = 0; j < TOPKz; j++) {
            int t = idx[b * TOPKz + j];
            s += sh[((size_t)b * Tz + t) * Pz + p];
        }
        agg[b * Pz + p] = s * (1.f / TOPKz);
    }
}

// ------------- fused classifier: c1 -> logits -> softmax -> cat_emb -> cross-q -----------------
__global__ __launch_bounds__(256) void cls_k(
    const float* __restrict__ agg,
    const float* __restrict__ cc_w1, const float* __restrict__ cc_b1,
    const float* __restrict__ g2, const float* __restrict__ b2,
    const float* __restrict__ m2, const float* __restrict__ v2,
    const float* __restrict__ cc_w2, const float* __restrict__ cc_b2,
    const float* __restrict__ ce,
    const float* __restrict__ ca_wqkv, const float* __restrict__ ca_bqkv,
    float* __restrict__ logits_out, float* __restrict__ qx)
{
    const int b = blockIdx.x, tid = threadIdx.x;
    __shared__ float ag[Pz], c1s[256], sm[16], cemb[256];
    ag[tid] = agg[b * Pz + tid];
    ag[tid + 256] = agg[b * Pz + tid + 256];
    __syncthreads();
    float s = 0.f;
    for (int p = 0; p < Pz; p++) s += ag[p] * cc_w1[p * 256 + tid];
    s += cc_b1[tid];
    s = (s - m2[tid]) * rsqrtf(v2[tid] + EPSz) * g2[tid] + b2[tid];
    s = fmaxf(s, 0.f);
    c1s[tid] = s;
    __syncthreads();
    if (tid < KC) {
        float l = 0.f;
        for (int e = 0; e < 256; e++) l += c1s[e] * cc_w2[e * KC + tid];
        l += cc_b2[tid];
        sm[tid] = l;
        logits_out[b * KC + tid] = l;
    }
    __syncthreads();
    if (tid == 0) {
        float mx = sm[0];
        for (int k = 1; k < KC; k++) mx = fmaxf(mx, sm[k]);
        float su = 0.f;
        for (int k = 0; k < KC; k++) { sm[k] = expf(sm[k] - mx); su += sm[k]; }
        float inv = 1.f / su;
        for (int k = 0; k < KC; k++) sm[k] *= inv;
    }
    __syncthreads();
    float cesum = 0.f;
    #pragma unroll
    for (int k = 0; k < KC; k++) cesum += sm[k] * ce[k * 256 + tid];
    cemb[tid] = cesum; __syncthreads();
    float q = 0.f;
    for (int i = 0; i < 256; i++) q += cemb[i] * ca_wqkv[i * 768 + tid];
    qx[b * 256 + tid] = q + ca_bqkv[tid];
}

// ------------- cross-attention (Tq=1) on combined kv[R,512] ------------------------------------
__global__ __launch_bounds__(256) void xattn_k(
    const float* __restrict__ qx, const float* __restrict__ kv, float* __restrict__ ctx)
{
    const int b = blockIdx.x, tid = threadIdx.x;
    __shared__ float q4[256];
    __shared__ float sc[NHz][Tz];
    q4[tid] = qx[b * 256 + tid];
    __syncthreads();
    for (int si = tid; si < NHz * Tz; si += 256) {
        int hh = si >> 9, t = si & (Tz - 1);
        const float* kr = kv + ((size_t)b * Tz + t) * 512 + hh * 64;
        const float* qr = q4 + hh * 64;
        float s = 0.f;
        #pragma unroll 8
        for (int d = 0; d < 64; d++) s += qr[d] * kr[d];
        sc[hh][t] = s * 0.125f;
    }
    __syncthreads();
    const int hh = tid >> 6, lane = tid & 63;
    float mx = -INFINITY;
    for (int t = lane; t < Tz; t += 64) mx = fmaxf(mx, sc[hh][t]);
    for (int off = 32; off > 0; off >>= 1) mx = fmaxf(mx, __shfl_xor(mx, off));
    float su = 0.f;
    for (int t = lane; t < Tz; t += 64) { float e = expf(sc[hh][t] - mx); sc[hh][t] = e; su += e; }
    for (int off = 32; off > 0; off >>= 1) su += __shfl_xor(su, off);
    float inv = 1.f / su;
    __syncthreads();
    float acc = 0.f;
    for (int t = 0; t < Tz; t++) acc += sc[hh][t] * kv[((size_t)b * Tz + t) * 512 + 256 + tid];
    ctx[b * 256 + tid] = acc * inv;
}

// ------------- ctx2 = ctx @ ca_wo + ca_bo ------------------------------------------------------
__global__ __launch_bounds__(256) void ctx2_k(
    const float* __restrict__ ctx, const float* __restrict__ ca_wo,
    const float* __restrict__ ca_bo, float* __restrict__ ctx2)
{
    const int b = blockIdx.x, tid = threadIdx.x;
    __shared__ float c[256];
    c[tid] = ctx[b * 256 + tid]; __syncthreads();
    float s = 0.f;
    for (int i = 0; i < 256; i++) s += c[i] * ca_wo[i * 256 + tid];
    ctx2[b * 256 + tid] = s + ca_bo[tid];
}

// ------------- fb = bf16(proj + ctx2) (broadcast over T) ---------------------------------------
__global__ __launch_bounds__(256) void addctx_k(
    const float* __restrict__ proj, const float* __restrict__ ctx2, ushort_t* __restrict__ fb)
{
    size_t idx = (size_t)blockIdx.x * 256 + threadIdx.x;   // over R*E
    int e = (int)(idx & 255);
    int b = (int)(idx >> 17);                              // T*E = 2^17
    fb[idx] = f2bf(proj[idx] + ctx2[b * 256 + e]);
}

// ==============================================================================================
extern "C" void kernel_launch(void* const* d_in, const int* in_sizes, int n_in,
                              void* d_out, int out_size, void* d_ws, size_t ws_size,
                              hipStream_t stream)
{
    const float* x       = (const float*)d_in[0];
    const float* pred_w  = (const float*)d_in[1];
    const float* pred_b  = (const float*)d_in[2];
    const float* t_wqkv  = (const float*)d_in[3];
    const float* t_bqkv  = (const float*)d_in[4];
    const float* t_wo    = (const float*)d_in[5];
    const float* t_bo    = (const float*)d_in[6];
    const float* t_ln1g  = (const float*)d_in[7];
    const float* t_ln1b  = (const float*)d_in[8];
    const float* t_w1    = (const float*)d_in[9];
    const float* t_b1    = (const float*)d_in[10];
    const float* t_w2    = (const float*)d_in[11];
    const float* t_b2    = (const float*)d_in[12];
    const float* t_ln2g  = (const float*)d_in[13];
    const float* t_ln2b  = (const float*)d_in[14];
    const float* sb_w    = (const float*)d_in[15];
    const float* sb_b    = (const float*)d_in[16];
    const float* bn1_g   = (const float*)d_in[17];
    const float* bn1_b   = (const float*)d_in[18];
    const float* bn1_m   = (const float*)d_in[19];
    const float* bn1_v   = (const float*)d_in[20];
    const float* dt_w    = (const float*)d_in[21];
    const float* dt_b    = (const float*)d_in[22];
    const float* cc_w1   = (const float*)d_in[23];
    const float* cc_b1   = (const float*)d_in[24];
    const float* bn2_g   = (const float*)d_in[25];
    const float* bn2_b   = (const float*)d_in[26];
    const float* bn2_m   = (const float*)d_in[27];
    const float* bn2_v   = (const float*)d_in[28];
    const float* cc_w2   = (const float*)d_in[29];
    const float* cc_b2   = (const float*)d_in[30];
    const float* ce      = (const float*)d_in[31];
    const float* kp_w    = (const float*)d_in[32];
    const float* kp_b    = (const float*)d_in[33];
    const float* ca_wqkv = (const float*)d_in[34];
    const float* ca_bqkv = (const float*)d_in[35];
    const float* ca_wo   = (const float*)d_in[36];
    const float* ca_bo   = (const float*)d_in[37];
    const float* fp_w    = (const float*)d_in[38];
    const float* fp_b    = (const float*)d_in[39];
    const float* df_w    = (const float*)d_in[40];
    const float* df_b    = (const float*)d_in[41];

    float* out = (float*)d_out;

    char* wp = (char*)d_ws;
    auto alloc = [&](size_t bytes) -> char* {
        char* r = wp; wp += (bytes + 255) & ~(size_t)255; return r;
    };
    float* scores  = (float*)alloc(BT * 4);
    int*   tkidx   = (int*)alloc(256 * 4);
    float* aggbuf  = (float*)alloc((size_t)Bz * Pz * 4);
    float* qxbuf   = (float*)alloc((size_t)Bz * Ez * 4);
    float* ctxbuf  = (float*)alloc((size_t)Bz * Ez * 4);
    float* ctx2buf = (float*)alloc((size_t)Bz * Ez * 4);

    const size_t WT_TOTAL = 2*(size_t)3072*1024 + 2*(size_t)1024*1024 + 2*(size_t)2048*1024
                          + 2*(size_t)1024*2048 + (size_t)512*1024 + (size_t)256*512
                          + 2*(size_t)256*256 + (size_t)1024*256;
    ushort_t* wtb = (ushort_t*)alloc(WT_TOTAL * 2);
    size_t woff = 0;
    auto nxt = [&](size_t n) -> ushort_t* { ushort_t* r = wtb + woff; woff += n; return r; };
    ushort_t* qkvT[2] = { nxt((size_t)3072*1024), nxt((size_t)3072*1024) };
    ushort_t* woT[2]  = { nxt((size_t)1024*1024), nxt((size_t)1024*1024) };
    ushort_t* w1T[2]  = { nxt((size_t)2048*1024), nxt((size_t)2048*1024) };
    ushort_t* w2T[2]  = { nxt((size_t)1024*2048), nxt((size_t)1024*2048) };
    ushort_t* sbT  = nxt((size_t)512*1024);
    ushort_t* kpT  = nxt((size_t)256*512);
    ushort_t* kvT  = nxt((size_t)512*256);   // combined cross k|v weight [512][256]
    ushort_t* fpT  = nxt((size_t)1024*256);

    // per-row bytes: h 4096 + hb 2048 + qkvb 6144 + scr 8192 + Pb 4096 + Vt 2048 = 26624
    size_t fixedB = (size_t)(wp - (char*)d_ws);
    int Bc = Bz;
    while (Bc > 1 && fixedB + (size_t)Bc * Tz * 26624 + 1048576 > ws_size) Bc >>= 1;
    const int Rmax = Bc * Tz;
    float*    h    = (float*)alloc((size_t)Rmax * 1024 * 4);
    ushort_t* hb   = (ushort_t*)alloc((size_t)Rmax * 1024 * 2);
    ushort_t* qkvb = (ushort_t*)alloc((size_t)Rmax * 3072 * 2);
    float*    scr  = (float*)alloc((size_t)Rmax * 2048 * 4);   // S / wo-out / ff2-out / tail f32
    ushort_t* Pb   = (ushort_t*)alloc((size_t)Rmax * 2048 * 2);
    ushort_t* Vt   = (ushort_t*)alloc((size_t)Rmax * 1024 * 2);

    // ---- one-time weight transpose+cast ----
    for (int l = 0; l < Lz; l++) {
        wt_k<<<dim3(3072/32, 1024/32), 256, 0, stream>>>(t_wqkv + (size_t)l*1024*3072, 3072, 1024, qkvT[l]);
        wt_k<<<dim3(1024/32, 1024/32), 256, 0, stream>>>(t_wo   + (size_t)l*1024*1024, 1024, 1024, woT[l]);
        wt_k<<<dim3(2048/32, 1024/32), 256, 0, stream>>>(t_w1   + (size_t)l*1024*2048, 2048, 1024, w1T[l]);
        wt_k<<<dim3(1024/32, 2048/32), 256, 0, stream>>>(t_w2   + (size_t)l*2048*1024, 1024, 2048, w2T[l]);
    }
    wt_k<<<dim3(512/32, 1024/32), 256, 0, stream>>>(sb_w, 512, 1024, sbT);
    wt_k<<<dim3(256/32,  512/32), 256, 0, stream>>>(kp_w, 256, 512, kpT);
    wt_k<<<dim3(256/32,  256/32), 256, 0, stream>>>(ca_wqkv + Ez,     768, 256, kvT);
    wt_k<<<dim3(256/32,  256/32), 256, 0, stream>>>(ca_wqkv + 2*Ez,   768, 256, kvT + (size_t)256*256);
    wt_k<<<dim3(1024/32, 256/32), 256, 0, stream>>>(fp_w, 1024, 256, fpT);

    for (int b0 = 0; b0 < Bz; b0 += Bc) {
        const int R = Bc * Tz;
        const float* xc = x + (size_t)b0 * Tz * Dz;

        auto MG = [&](const ushort_t* Ain, int lda, const ushort_t* Wt_, const float* bias,
                      float* Cf, ushort_t* Ch, int ldc, int N, int Kd, int epi,
                      const float* g = nullptr, const float* bb = nullptr,
                      const float* m = nullptr, const float* v = nullptr) {
            mgemm_k<<<dim3(N/128, R/128), 256, 0, stream>>>(
                Ain, lda, Wt_, bias, Cf, Ch, ldc, Kd, epi, g, bb, m, v);
        };
        auto MG8 = [&](const ushort_t* Ain, int lda, const ushort_t* Wt_, const float* bias,
                       float* Cf, ushort_t* Ch, int ldc, int N, int Kd, int epi) {
            mgemm8_k<<<dim3(N/256, R/256), 512, 0, stream>>>(
                Ain, lda, Wt_, bias, Cf, Ch, ldc, Kd, epi,
                nullptr, nullptr, nullptr, nullptr);
        };

        // 1. fused shift-predictor + TSM -> h, hb
        predshift_k<<<R, 256, 0, stream>>>(xc, pred_w, pred_b, h, hb);

        // 2. transformer layers
        for (int l = 0; l < Lz; l++) {
            MG8(hb, 1024, qkvT[l], t_bqkv + (size_t)l*3072, nullptr, qkvb, 3072, 3072, 1024, 0);
            vtb_k<<<dim3(8, 16, Bc * 4), 256, 0, stream>>>(qkvb, Vt);
            bgemm_k<<<dim3(4, 4, Bc * 4), 256, 0, stream>>>(
                qkvb, 3072, (size_t)512 * 3072, 256,
                qkvb + 1024, 3072, (size_t)512 * 3072, 256,
                scr, nullptr, 512, (size_t)4 * 512 * 512, 512 * 512, 256);
            softmax_k<<<R, 256, 0, stream>>>(scr, Pb);
            bgemm_k<<<dim3(2, 4, Bc * 4), 256, 0, stream>>>(
                Pb, 512, (size_t)4 * 512 * 512, 512 * 512,
                Vt, 512, (size_t)4 * 256 * 512, 256 * 512,
                nullptr, qkvb, 3072, (size_t)512 * 3072, 256, 512);
            MG8(qkvb, 3072, woT[l], t_bo + (size_t)l*1024, scr, nullptr, 1024, 1024, 1024, 0);
            addln_k<<<R, 256, 0, stream>>>(h, hb, scr, 1024,
                                           t_ln1g + (size_t)l*Dz, t_ln1b + (size_t)l*Dz);
            MG8(hb, 1024, w1T[l], t_b1 + (size_t)l*FFz, nullptr, qkvb, 2048, 2048, 1024, 1);
            MG8(qkvb, 2048, w2T[l], t_b2 + (size_t)l*Dz, scr, nullptr, 1024, 1024, 2048, 0);
            addln_k<<<R, 256, 0, stream>>>(h, hb, scr, 1024,
                                           t_ln2g + (size_t)l*Dz, t_ln2b + (size_t)l*Dz);
        }

        // tail buffers sublet scr (f32) and Pb (bf16)
        float*    shared  = scr;                       // [R,512]
        float*    proj    = scr + (size_t)R * 512;     // [R,256]
        float*    kvb     = scr + (size_t)R * 768;     // [R,512] combined k|v
        float*    fin     = scr + (size_t)R * 1280;    // [R,512]
        ushort_t* sharedb = Pb;                        // [R,512]
        ushort_t* projb   = Pb + (size_t)R * 512;      // [R,256]
        ushort_t* fb      = Pb + (size_t)R * 768;      // [R,256]
        ushort_t* fpb     = qkvb;                      // [R,1024]

        // 3. shared = relu(BN1(h @ sb_w + sb_b))  (dual out)
        MG(hb, 1024, sbT, sb_b, shared, sharedb, 512, 512, 1024, 2, bn1_g, bn1_b, bn1_m, bn1_v);
        // 4. scores, top-k, agg, classifier
        rowdot_k<<<R, 256, 0, stream>>>(shared, dt_w, dt_b, scores + (size_t)b0 * Tz);
        topk_k<<<Bc, 256, 0, stream>>>(scores + (size_t)b0 * Tz, tkidx);
        agg_k<<<Bc, 256, 0, stream>>>(shared, tkidx, aggbuf);
        cls_k<<<Bc, 256, 0, stream>>>(aggbuf, cc_w1, cc_b1, bn2_g, bn2_b, bn2_m, bn2_v,
                                      cc_w2, cc_b2, ce, ca_wqkv, ca_bqkv,
                                      out + BT + (size_t)b0 * KC, qxbuf);
        // 5. proj (dual), combined cross k|v
        MG(sharedb, 512, kpT, kp_b, proj, projb, 256, 256, 512, 0);
        MG(projb, 256, kvT, ca_bqkv + Ez, kvb, nullptr, 512, 512, 256, 0);
        // 6. cross attention + final fuse
        xattn_k<<<Bc, 256, 0, stream>>>(qxbuf, kvb, ctxbuf);
        ctx2_k<<<Bc, 256, 0, stream>>>(ctxbuf, ca_wo, ca_bo, ctx2buf);
        addctx_k<<<(R * Ez) / 256, 256, 0, stream>>>(proj, ctx2buf, fb);
        // 7. fp_out (bf16) -> fin (BN+relu fp32) -> seg
        MG(fb, 256, fpT, fp_b, nullptr, fpb, 1024, 1024, 256, 0);
        MG(fpb, 1024, sbT, sb_b, fin, nullptr, 512, 512, 1024, 2, bn1_g, bn1_b, bn1_m, bn1_v);
        rowdot_k<<<R, 256, 0, stream>>>(fin, df_w, df_b, out + (size_t)b0 * Tz);
    }
}

// Round 8
// 1993.676 us; speedup vs baseline: 1.0641x; 1.0356x over previous
//
#include <hip/hip_runtime.h>
#include <math.h>

#define Bz 32
#define Tz 512
#define Dz 1024
#define Pz 512
#define Ez 256
#define KC 14
#define NHz 4
#define Lz 2
#define FFz 2048
#define TOPKz 7
#define EPSz 1e-5f
#define BT (Bz*Tz)

typedef unsigned short ushort_t;
typedef __attribute__((ext_vector_type(8))) short short8;
typedef __attribute__((ext_vector_type(4))) float f32x4;

__device__ __forceinline__ ushort_t f2bf(float f) {
    union { float f; unsigned int u; } x; x.f = f;
    unsigned int r = x.u + 0x7fffu + ((x.u >> 16) & 1u);   // RNE (finite inputs)
    return (ushort_t)(r >> 16);
}
__device__ __forceinline__ float bf2f(ushort_t h) {
    union { unsigned int u; float f; } x; x.u = ((unsigned int)h) << 16; return x.f;
}

// ---------------- 128x128 bf16 MFMA GEMM (m97 structure): C = A @ W^T (+bias, epi) -------------
// Dual outputs: Cf (fp32) and/or Ch (bf16), either may be null. epi: 0=none,1=relu,2=BN+relu
__global__ __launch_bounds__(256) void mgemm_k(
    const ushort_t* __restrict__ A, int lda,
    const ushort_t* __restrict__ Wt,
    const float* __restrict__ bias,
    float* __restrict__ Cf, ushort_t* __restrict__ Ch, int ldc,
    int Kd, int epi,
    const float* __restrict__ bng, const float* __restrict__ bnb,
    const float* __restrict__ bnm, const float* __restrict__ bnv)
{
    __shared__ __align__(16) ushort_t As[128 * 32];
    __shared__ __align__(16) ushort_t Bs[128 * 32];
    const int tid = threadIdx.x;
    const int lane = tid & 63, wid = tid >> 6;
    const int row0 = blockIdx.y * 128, col0 = blockIdx.x * 128;
    const int wrow = (wid >> 1) * 64, wcol = (wid & 1) * 64;
    const int srow = (lane >> 2);
    const int skoff = (lane & 3) * 8;

    f32x4 acc[4][4];
    const f32x4 zr = {0.f, 0.f, 0.f, 0.f};
    #pragma unroll
    for (int m = 0; m < 4; m++)
        #pragma unroll
        for (int n = 0; n < 4; n++) acc[m][n] = zr;

    for (int k0 = 0; k0 < Kd; k0 += 32) {
        #pragma unroll
        for (int j = 0; j < 2; j++) {
            const int r = wid * 32 + j * 16;
            const ushort_t* ga = A + (size_t)(row0 + r + srow) * lda + k0 + skoff;
            __builtin_amdgcn_global_load_lds(
                (const __attribute__((address_space(1))) unsigned int*)ga,
                (__attribute__((address_space(3))) unsigned int*)(As + r * 32), 16, 0, 0);
            const ushort_t* gb = Wt + (size_t)(col0 + r + srow) * Kd + k0 + skoff;
            __builtin_amdgcn_global_load_lds(
                (const __attribute__((address_space(1))) unsigned int*)gb,
                (__attribute__((address_space(3))) unsigned int*)(Bs + r * 32), 16, 0, 0);
        }
        __syncthreads();
        short8 af[4], bf[4];
        #pragma unroll
        for (int m = 0; m < 4; m++)
            af[m] = *(const short8*)(As + (wrow + m * 16 + (lane & 15)) * 32 + (lane >> 4) * 8);
        #pragma unroll
        for (int n = 0; n < 4; n++)
            bf[n] = *(const short8*)(Bs + (wcol + n * 16 + (lane & 15)) * 32 + (lane >> 4) * 8);
        #pragma unroll
        for (int m = 0; m < 4; m++)
            #pragma unroll
            for (int n = 0; n < 4; n++)
                acc[m][n] = __builtin_amdgcn_mfma_f32_16x16x32_bf16(af[m], bf[n], acc[m][n], 0, 0, 0);
        __syncthreads();
    }

    #pragma unroll
    for (int n = 0; n < 4; n++) {
        const int ccol = col0 + wcol + n * 16 + (lane & 15);
        const float bb = bias[ccol];
        float bsc = 1.f, bsh = 0.f;
        if (epi == 2) {
            bsc = rsqrtf(bnv[ccol] + EPSz) * bng[ccol];
            bsh = bnb[ccol] - bnm[ccol] * bsc;
        }
        #pragma unroll
        for (int m = 0; m < 4; m++) {
            #pragma unroll
            for (int r = 0; r < 4; r++) {
                const int crow = row0 + wrow + m * 16 + (lane >> 4) * 4 + r;
                float y = acc[m][n][r] + bb;
                if (epi == 2) y = y * bsc + bsh;
                if (epi >= 1) y = fmaxf(y, 0.f);
                if (Cf) Cf[(size_t)crow * ldc + ccol] = y;
                if (Ch) Ch[(size_t)crow * ldc + ccol] = f2bf(y);
            }
        }
    }
}

// ---------------- batched bf16 MFMA GEMM over z=(batch,head): fp32 OR bf16 out -----------------
__global__ __launch_bounds__(256) void bgemm_k(
    const ushort_t* __restrict__ A0, int lda, size_t Abz, int Ahz,
    const ushort_t* __restrict__ W0, int ldw, size_t Wbz, int Whz,
    float* __restrict__ Cf0, ushort_t* __restrict__ Ch0, int ldc, size_t Cbz, int Chz, int Kd)
{
    const int z = blockIdx.z, bl = z >> 2, hh = z & 3;
    const ushort_t* A = A0 + (size_t)bl * Abz + (size_t)hh * Ahz;
    const ushort_t* W = W0 + (size_t)bl * Wbz + (size_t)hh * Whz;

    __shared__ __align__(16) ushort_t As[128 * 32];
    __shared__ __align__(16) ushort_t Bs[128 * 32];
    const int tid = threadIdx.x;
    const int lane = tid & 63, wid = tid >> 6;
    const int row0 = blockIdx.y * 128, col0 = blockIdx.x * 128;
    const int wrow = (wid >> 1) * 64, wcol = (wid & 1) * 64;
    const int srow = (lane >> 2);
    const int skoff = (lane & 3) * 8;

    f32x4 acc[4][4];
    const f32x4 zr = {0.f, 0.f, 0.f, 0.f};
    #pragma unroll
    for (int m = 0; m < 4; m++)
        #pragma unroll
        for (int n = 0; n < 4; n++) acc[m][n] = zr;

    for (int k0 = 0; k0 < Kd; k0 += 32) {
        #pragma unroll
        for (int j = 0; j < 2; j++) {
            const int r = wid * 32 + j * 16;
            const ushort_t* ga = A + (size_t)(row0 + r + srow) * lda + k0 + skoff;
            __builtin_amdgcn_global_load_lds(
                (const __attribute__((address_space(1))) unsigned int*)ga,
                (__attribute__((address_space(3))) unsigned int*)(As + r * 32), 16, 0, 0);
            const ushort_t* gb = W + (size_t)(col0 + r + srow) * ldw + k0 + skoff;
            __builtin_amdgcn_global_load_lds(
                (const __attribute__((address_space(1))) unsigned int*)gb,
                (__attribute__((address_space(3))) unsigned int*)(Bs + r * 32), 16, 0, 0);
        }
        __syncthreads();
        short8 af[4], bf[4];
        #pragma unroll
        for (int m = 0; m < 4; m++)
            af[m] = *(const short8*)(As + (wrow + m * 16 + (lane & 15)) * 32 + (lane >> 4) * 8);
        #pragma unroll
        for (int n = 0; n < 4; n++)
            bf[n] = *(const short8*)(Bs + (wcol + n * 16 + (lane & 15)) * 32 + (lane >> 4) * 8);
        #pragma unroll
        for (int m = 0; m < 4; m++)
            #pragma unroll
            for (int n = 0; n < 4; n++)
                acc[m][n] = __builtin_amdgcn_mfma_f32_16x16x32_bf16(af[m], bf[n], acc[m][n], 0, 0, 0);
        __syncthreads();
    }

    #pragma unroll
    for (int n = 0; n < 4; n++) {
        const int ccol = col0 + wcol + n * 16 + (lane & 15);
        #pragma unroll
        for (int m = 0; m < 4; m++) {
            #pragma unroll
            for (int r = 0; r < 4; r++) {
                const int crow = row0 + wrow + m * 16 + (lane >> 4) * 4 + r;
                const float y = acc[m][n][r];
                if (Cf0) (Cf0 + (size_t)bl * Cbz + (size_t)hh * Chz)[(size_t)crow * ldc + ccol] = y;
                if (Ch0) (Ch0 + (size_t)bl * Cbz + (size_t)hh * Chz)[(size_t)crow * ldc + ccol] = f2bf(y);
            }
        }
    }
}

// ------------- softmax over S rows (scale 1/16), write normalized P in bf16 --------------------
__global__ __launch_bounds__(256) void softmax_k(
    const float* __restrict__ S, ushort_t* __restrict__ P)
{
    const int row = blockIdx.x * 4 + (threadIdx.x >> 6);
    const int lane = threadIdx.x & 63;
    const float* sr = S + (size_t)row * 512 + lane * 8;
    const float4 a = *(const float4*)sr;
    const float4 b = *(const float4*)(sr + 4);
    float v[8] = {a.x, a.y, a.z, a.w, b.x, b.y, b.z, b.w};
    #pragma unroll
    for (int i = 0; i < 8; i++) v[i] *= 0.0625f;
    float m = v[0];
    #pragma unroll
    for (int i = 1; i < 8; i++) m = fmaxf(m, v[i]);
    #pragma unroll
    for (int off = 32; off > 0; off >>= 1) m = fmaxf(m, __shfl_xor(m, off));
    float s = 0.f;
    #pragma unroll
    for (int i = 0; i < 8; i++) { v[i] = expf(v[i] - m); s += v[i]; }
    #pragma unroll
    for (int off = 32; off > 0; off >>= 1) s += __shfl_xor(s, off);
    const float inv = 1.f / s;
    union { ushort_t h[8]; uint4 u; } pk;
    #pragma unroll
    for (int i = 0; i < 8; i++) pk.h[i] = f2bf(v[i] * inv);
    *(uint4*)(P + (size_t)row * 512 + lane * 8) = pk.u;
}

// ------------- z-batched bf16 transpose: V[kv][d] (qkvb v-slots) -> Vt[d][kv] ------------------
__global__ __launch_bounds__(256) void vtb_k(
    const ushort_t* __restrict__ qkvb, ushort_t* __restrict__ Vt)
{
    const int z = blockIdx.z, bl = z >> 2, hh = z & 3;
    const ushort_t* src = qkvb + (size_t)bl * 512 * 3072 + 2048 + hh * 256;
    ushort_t* dst = Vt + (size_t)z * 256 * 512;
    __shared__ ushort_t t[32][33];
    const int tx = threadIdx.x & 31, ty = threadIdx.x >> 5;
    const int gx = blockIdx.x * 32;   // d
    const int gy = blockIdx.y * 32;   // kv
    #pragma unroll
    for (int i = 0; i < 4; i++) {
        const int row = ty + i * 8;
        t[row][tx] = src[(size_t)(gy + row) * 3072 + gx + tx];
    }
    __syncthreads();
    #pragma unroll
    for (int i = 0; i < 4; i++) {
        const int nr = ty + i * 8;
        dst[(size_t)(gx + nr) * 512 + gy + tx] = t[tx][nr];
    }
}

// ------------- transpose+cast weight: src fp32 [Kd][N] (row stride ld) -> dst bf16 [N][Kd] -----
__global__ __launch_bounds__(256) void wt_k(
    const float* __restrict__ src, int ld, int Kd, ushort_t* __restrict__ dst)
{
    __shared__ float t[32][33];
    const int tx = threadIdx.x & 31, ty = threadIdx.x >> 5;
    const int gx = blockIdx.x * 32;
    const int gy = blockIdx.y * 32;
    #pragma unroll
    for (int i = 0; i < 4; i++) {
        const int row = ty + i * 8;
        t[row][tx] = src[(size_t)(gy + row) * ld + gx + tx];
    }
    __syncthreads();
    #pragma unroll
    for (int i = 0; i < 4; i++) {
        const int nr = ty + i * 8;
        dst[(size_t)(gx + nr) * Kd + gy + tx] = f2bf(t[tx][nr]);
    }
}

// ------------- fused shift-predictor + TSM shift (dual fp32/bf16 out) --------------------------
__global__ __launch_bounds__(256) void predshift_k(
    const float* __restrict__ x, const float* __restrict__ pred_w,
    const float* __restrict__ pred_b, float* __restrict__ h, ushort_t* __restrict__ hb)
{
    const int row = blockIdx.x, tid = threadIdx.x;
    const size_t base = (size_t)row * Dz;
    float s = 0.f;
    #pragma unroll
    for (int i = 0; i < 4; i++) {
        int c = tid + i * 256;
        s += x[base + c] * pred_w[c];
    }
    __shared__ float red[256];
    __shared__ int sns;
    red[tid] = s; __syncthreads();
    for (int off = 128; off > 0; off >>= 1) {
        if (tid < off) red[tid] += red[tid + off];
        __syncthreads();
    }
    if (tid == 0) {
        float sg = 1.f / (1.f + expf(-(red[0] + pred_b[0])));
        sns = (int)(sg * (float)(Dz / 2));
    }
    __syncthreads();
    const int sn = sns;
    const int t = row & (Tz - 1);
    #pragma unroll
    for (int i = 0; i < 4; i++) {
        const int c = tid + i * 256;
        const size_t idx = base + c;
        float v;
        if (c < sn)          v = (t > 0)      ? x[idx - Dz] : 0.f;
        else if (c < 2 * sn) v = (t < Tz - 1) ? x[idx + Dz] : 0.f;
        else                 v = x[idx];
        h[idx] = v; hb[idx] = f2bf(v);
    }
}

// ------------- h = LN(h + r_bf16); dual write h fp32 + hb bf16 ---------------------------------
__global__ __launch_bounds__(256) void addlnb_k(
    float* __restrict__ h, ushort_t* __restrict__ hb,
    const ushort_t* __restrict__ r,
    const float* __restrict__ g, const float* __restrict__ b)
{
    const int row = blockIdx.x, tid = threadIdx.x;
    const size_t base = (size_t)row * Dz;
    float x[4]; float s = 0.f, sq = 0.f;
    #pragma unroll
    for (int i = 0; i < 4; i++) {
        const int c = tid + i * 256;
        x[i] = h[base + c] + bf2f(r[base + c]);
        s += x[i]; sq += x[i] * x[i];
    }
    __shared__ float rs[256], rq[256];
    rs[tid] = s; rq[tid] = sq; __syncthreads();
    for (int off = 128; off > 0; off >>= 1) {
        if (tid < off) { rs[tid] += rs[tid + off]; rq[tid] += rq[tid + off]; }
        __syncthreads();
    }
    float mean = rs[0] * (1.f / Dz);
    float var = rq[0] * (1.f / Dz) - mean * mean;
    float inv = rsqrtf(var + EPSz);
    #pragma unroll
    for (int i = 0; i < 4; i++) {
        int c = tid + i * 256;
        float y = (x[i] - mean) * inv * g[c] + b[c];
        h[base + c] = y; hb[base + c] = f2bf(y);
    }
}

// ------------- rowdot: out[row] = dot(in[row,:512], w) + b -------------------------------------
__global__ __launch_bounds__(256) void rowdot_k(
    const float* __restrict__ in, const float* __restrict__ w,
    const float* __restrict__ bptr, float* __restrict__ outf)
{
    const int row = blockIdx.x, tid = threadIdx.x;
    const float* r = in + (size_t)row * Pz;
    float s = 0.f;
    #pragma unroll
    for (int c = tid; c < Pz; c += 256) s += r[c] * w[c];
    __shared__ float red[256];
    red[tid] = s; __syncthreads();
    for (int off = 128; off > 0; off >>= 1) {
        if (tid < off) red[tid] += red[tid + off];
        __syncthreads();
    }
    if (tid == 0) outf[row] = red[0] + bptr[0];
}

// ------------- top-k (7 of 512) per (chunk-local) batch row ------------------------------------
__global__ __launch_bounds__(256) void topk_k(const float* __restrict__ scores, int* __restrict__ idx)
{
    const int b = blockIdx.x, tid = threadIdx.x;
    __shared__ float sv[Tz];
    __shared__ float rv[256]; __shared__ int ri[256];
    sv[tid] = scores[b * Tz + tid];
    sv[tid + 256] = scores[b * Tz + tid + 256];
    __syncthreads();
    for (int it = 0; it < TOPKz; it++) {
        float v0 = sv[tid]; int i0 = tid;
        float v1 = sv[tid + 256];
        if (v1 > v0) { v0 = v1; i0 = tid + 256; }
        rv[tid] = v0; ri[tid] = i0; __syncthreads();
        for (int off = 128; off > 0; off >>= 1) {
            if (tid < off) {
                if (rv[tid + off] > rv[tid] ||
                    (rv[tid + off] == rv[tid] && ri[tid + off] < ri[tid])) {
                    rv[tid] = rv[tid + off]; ri[tid] = ri[tid + off];
                }
            }
            __syncthreads();
        }
        if (tid == 0) { idx[b * TOPKz + it] = ri[0]; sv[ri[0]] = -INFINITY; }
        __syncthreads();
    }
}

// ------------- agg = mean of top-k rows of shared ---------------------------------------------
__global__ __launch_bounds__(256) void agg_k(
    const float* __restrict__ sh, const int* __restrict__ idx, float* __restrict__ agg)
{
    const int b = blockIdx.x, tid = threadIdx.x;
    for (int p = tid; p < Pz; p += 256) {
        float s = 0.f;
        #pragma unroll
        for (int j = 0; j < TOPKz; j++) {
            int t = idx[b * TOPKz + j];
            s += sh[((size_t)b * Tz + t) * Pz + p];
        }
        agg[b * Pz + p] = s * (1.f / TOPKz);
    }
}

// ------------- fused classifier: c1 -> logits -> softmax -> cat_emb -> cross-q -----------------
__global__ __launch_bounds__(256) void cls_k(
    const float* __restrict__ agg,
    const float* __restrict__ cc_w1, const float* __restrict__ cc_b1,
    const float* __restrict__ g2, const float* __restrict__ b2,
    const float* __restrict__ m2, const float* __restrict__ v2,
    const float* __restrict__ cc_w2, const float* __restrict__ cc_b2,
    const float* __restrict__ ce,
    const float* __restrict__ ca_wqkv, const float* __restrict__ ca_bqkv,
    float* __restrict__ logits_out, float* __restrict__ qx)
{
    const int b = blockIdx.x, tid = threadIdx.x;
    __shared__ float ag[Pz], c1s[256], sm[16], cemb[256];
    ag[tid] = agg[b * Pz + tid];
    ag[tid + 256] = agg[b * Pz + tid + 256];
    __syncthreads();
    float s = 0.f;
    for (int p = 0; p < Pz; p++) s += ag[p] * cc_w1[p * 256 + tid];
    s += cc_b1[tid];
    s = (s - m2[tid]) * rsqrtf(v2[tid] + EPSz) * g2[tid] + b2[tid];
    s = fmaxf(s, 0.f);
    c1s[tid] = s;
    __syncthreads();
    if (tid < KC) {
        float l = 0.f;
        for (int e = 0; e < 256; e++) l += c1s[e] * cc_w2[e * KC + tid];
        l += cc_b2[tid];
        sm[tid] = l;
        logits_out[b * KC + tid] = l;
    }
    __syncthreads();
    if (tid == 0) {
        float mx = sm[0];
        for (int k = 1; k < KC; k++) mx = fmaxf(mx, sm[k]);
        float su = 0.f;
        for (int k = 0; k < KC; k++) { sm[k] = expf(sm[k] - mx); su += sm[k]; }
        float inv = 1.f / su;
        for (int k = 0; k < KC; k++) sm[k] *= inv;
    }
    __syncthreads();
    float cesum = 0.f;
    #pragma unroll
    for (int k = 0; k < KC; k++) cesum += sm[k] * ce[k * 256 + tid];
    cemb[tid] = cesum; __syncthreads();
    float q = 0.f;
    for (int i = 0; i < 256; i++) q += cemb[i] * ca_wqkv[i * 768 + tid];
    qx[b * 256 + tid] = q + ca_bqkv[tid];
}

// ------------- cross-attention (Tq=1) on combined kv[R,512] + fused wo projection --------------
__global__ __launch_bounds__(256) void xattn_k(
    const float* __restrict__ qx, const float* __restrict__ kv,
    const float* __restrict__ ca_wo, const float* __restrict__ ca_bo,
    float* __restrict__ ctx2)
{
    const int b = blockIdx.x, tid = threadIdx.x;
    __shared__ float q4[256];
    __shared__ float sc[NHz][Tz];
    __shared__ float cx[256];
    q4[tid] = qx[b * 256 + tid];
    __syncthreads();
    for (int si = tid; si < NHz * Tz; si += 256) {
        int hh = si >> 9, t = si & (Tz - 1);
        const float* kr = kv + ((size_t)b * Tz + t) * 512 + hh * 64;
        const float* qr = q4 + hh * 64;
        float s = 0.f;
        #pragma unroll 8
        for (int d = 0; d < 64; d++) s += qr[d] * kr[d];
        sc[hh][t] = s * 0.125f;
    }
    __syncthreads();
    const int hh = tid >> 6, lane = tid & 63;
    float mx = -INFINITY;
    for (int t = lane; t < Tz; t += 64) mx = fmaxf(mx, sc[hh][t]);
    for (int off = 32; off > 0; off >>= 1) mx = fmaxf(mx, __shfl_xor(mx, off));
    float su = 0.f;
    for (int t = lane; t < Tz; t += 64) { float e = expf(sc[hh][t] - mx); sc[hh][t] = e; su += e; }
    for (int off = 32; off > 0; off >>= 1) su += __shfl_xor(su, off);
    float inv = 1.f / su;
    __syncthreads();
    float acc = 0.f;
    for (int t = 0; t < Tz; t++) acc += sc[hh][t] * kv[((size_t)b * Tz + t) * 512 + 256 + tid];
    cx[tid] = acc * inv;
    __syncthreads();
    float s2 = 0.f;
    for (int i = 0; i < 256; i++) s2 += cx[i] * ca_wo[i * 256 + tid];
    ctx2[b * 256 + tid] = s2 + ca_bo[tid];
}

// ------------- fb = bf16(proj + ctx2) (broadcast over T) ---------------------------------------
__global__ __launch_bounds__(256) void addctx_k(
    const float* __restrict__ proj, const float* __restrict__ ctx2, ushort_t* __restrict__ fb)
{
    size_t idx = (size_t)blockIdx.x * 256 + threadIdx.x;   // over R*E
    int e = (int)(idx & 255);
    int b = (int)(idx >> 17);                              // T*E = 2^17
    fb[idx] = f2bf(proj[idx] + ctx2[b * 256 + e]);
}

// ==============================================================================================
extern "C" void kernel_launch(void* const* d_in, const int* in_sizes, int n_in,
                              void* d_out, int out_size, void* d_ws, size_t ws_size,
                              hipStream_t stream)
{
    const float* x       = (const float*)d_in[0];
    const float* pred_w  = (const float*)d_in[1];
    const float* pred_b  = (const float*)d_in[2];
    const float* t_wqkv  = (const float*)d_in[3];
    const float* t_bqkv  = (const float*)d_in[4];
    const float* t_wo    = (const float*)d_in[5];
    const float* t_bo    = (const float*)d_in[6];
    const float* t_ln1g  = (const float*)d_in[7];
    const float* t_ln1b  = (const float*)d_in[8];
    const float* t_w1    = (const float*)d_in[9];
    const float* t_b1    = (const float*)d_in[10];
    const float* t_w2    = (const float*)d_in[11];
    const float* t_b2    = (const float*)d_in[12];
    const float* t_ln2g  = (const float*)d_in[13];
    const float* t_ln2b  = (const float*)d_in[14];
    const float* sb_w    = (const float*)d_in[15];
    const float* sb_b    = (const float*)d_in[16];
    const float* bn1_g   = (const float*)d_in[17];
    const float* bn1_b   = (const float*)d_in[18];
    const float* bn1_m   = (const float*)d_in[19];
    const float* bn1_v   = (const float*)d_in[20];
    const float* dt_w    = (const float*)d_in[21];
    const float* dt_b    = (const float*)d_in[22];
    const float* cc_w1   = (const float*)d_in[23];
    const float* cc_b1   = (const float*)d_in[24];
    const float* bn2_g   = (const float*)d_in[25];
    const float* bn2_b   = (const float*)d_in[26];
    const float* bn2_m   = (const float*)d_in[27];
    const float* bn2_v   = (const float*)d_in[28];
    const float* cc_w2   = (const float*)d_in[29];
    const float* cc_b2   = (const float*)d_in[30];
    const float* ce      = (const float*)d_in[31];
    const float* kp_w    = (const float*)d_in[32];
    const float* kp_b    = (const float*)d_in[33];
    const float* ca_wqkv = (const float*)d_in[34];
    const float* ca_bqkv = (const float*)d_in[35];
    const float* ca_wo   = (const float*)d_in[36];
    const float* ca_bo   = (const float*)d_in[37];
    const float* fp_w    = (const float*)d_in[38];
    const float* fp_b    = (const float*)d_in[39];
    const float* df_w    = (const float*)d_in[40];
    const float* df_b    = (const float*)d_in[41];

    float* out = (float*)d_out;

    char* wp = (char*)d_ws;
    auto alloc = [&](size_t bytes) -> char* {
        char* r = wp; wp += (bytes + 255) & ~(size_t)255; return r;
    };
    float* scores  = (float*)alloc(BT * 4);
    int*   tkidx   = (int*)alloc(256 * 4);
    float* aggbuf  = (float*)alloc((size_t)Bz * Pz * 4);
    float* qxbuf   = (float*)alloc((size_t)Bz * Ez * 4);
    float* ctx2buf = (float*)alloc((size_t)Bz * Ez * 4);

    const size_t WT_TOTAL = 2*(size_t)3072*1024 + 2*(size_t)1024*1024 + 2*(size_t)2048*1024
                          + 2*(size_t)1024*2048 + (size_t)512*1024 + (size_t)256*512
                          + 2*(size_t)256*256 + (size_t)1024*256;
    ushort_t* wtb = (ushort_t*)alloc(WT_TOTAL * 2);
    size_t woff = 0;
    auto nxt = [&](size_t n) -> ushort_t* { ushort_t* r = wtb + woff; woff += n; return r; };
    ushort_t* qkvT[2] = { nxt((size_t)3072*1024), nxt((size_t)3072*1024) };
    ushort_t* woT[2]  = { nxt((size_t)1024*1024), nxt((size_t)1024*1024) };
    ushort_t* w1T[2]  = { nxt((size_t)2048*1024), nxt((size_t)2048*1024) };
    ushort_t* w2T[2]  = { nxt((size_t)1024*2048), nxt((size_t)1024*2048) };
    ushort_t* sbT  = nxt((size_t)512*1024);
    ushort_t* kpT  = nxt((size_t)256*512);
    ushort_t* kvT  = nxt((size_t)512*256);   // combined cross k|v weight [512][256]
    ushort_t* fpT  = nxt((size_t)1024*256);

    // per-row bytes: h 4096 + hb 2048 + qkvb 6144 + scr 8192 + Pb 4096 + Vt 2048 = 26624
    size_t fixedB = (size_t)(wp - (char*)d_ws);
    int Bc = Bz;
    while (Bc > 1 && fixedB + (size_t)Bc * Tz * 26624 + 1048576 > ws_size) Bc >>= 1;
    const int Rmax = Bc * Tz;
    float*    h    = (float*)alloc((size_t)Rmax * 1024 * 4);
    ushort_t* hb   = (ushort_t*)alloc((size_t)Rmax * 1024 * 2);
    ushort_t* qkvb = (ushort_t*)alloc((size_t)Rmax * 3072 * 2);
    float*    scr  = (float*)alloc((size_t)Rmax * 2048 * 4);   // S / tail f32
    ushort_t* Pb   = (ushort_t*)alloc((size_t)Rmax * 2048 * 2); // P / wo-out / ff2-out / tail bf16
    ushort_t* Vt   = (ushort_t*)alloc((size_t)Rmax * 1024 * 2);

    // ---- one-time weight transpose+cast ----
    for (int l = 0; l < Lz; l++) {
        wt_k<<<dim3(3072/32, 1024/32), 256, 0, stream>>>(t_wqkv + (size_t)l*1024*3072, 3072, 1024, qkvT[l]);
        wt_k<<<dim3(1024/32, 1024/32), 256, 0, stream>>>(t_wo   + (size_t)l*1024*1024, 1024, 1024, woT[l]);
        wt_k<<<dim3(2048/32, 1024/32), 256, 0, stream>>>(t_w1   + (size_t)l*1024*2048, 2048, 1024, w1T[l]);
        wt_k<<<dim3(1024/32, 2048/32), 256, 0, stream>>>(t_w2   + (size_t)l*2048*1024, 1024, 2048, w2T[l]);
    }
    wt_k<<<dim3(512/32, 1024/32), 256, 0, stream>>>(sb_w, 512, 1024, sbT);
    wt_k<<<dim3(256/32,  512/32), 256, 0, stream>>>(kp_w, 256, 512, kpT);
    wt_k<<<dim3(256/32,  256/32), 256, 0, stream>>>(ca_wqkv + Ez,     768, 256, kvT);
    wt_k<<<dim3(256/32,  256/32), 256, 0, stream>>>(ca_wqkv + 2*Ez,   768, 256, kvT + (size_t)256*256);
    wt_k<<<dim3(1024/32, 256/32), 256, 0, stream>>>(fp_w, 1024, 256, fpT);

    for (int b0 = 0; b0 < Bz; b0 += Bc) {
        const int R = Bc * Tz;
        const float* xc = x + (size_t)b0 * Tz * Dz;

        auto MG = [&](const ushort_t* Ain, int lda, const ushort_t* Wt_, const float* bias,
                      float* Cf, ushort_t* Ch, int ldc, int N, int Kd, int epi,
                      const float* g = nullptr, const float* bb = nullptr,
                      const float* m = nullptr, const float* v = nullptr) {
            mgemm_k<<<dim3(N/128, R/128), 256, 0, stream>>>(
                Ain, lda, Wt_, bias, Cf, Ch, ldc, Kd, epi, g, bb, m, v);
        };

        // 1. fused shift-predictor + TSM -> h, hb
        predshift_k<<<R, 256, 0, stream>>>(xc, pred_w, pred_b, h, hb);

        // 2. transformer layers
        for (int l = 0; l < Lz; l++) {
            MG(hb, 1024, qkvT[l], t_bqkv + (size_t)l*3072, nullptr, qkvb, 3072, 3072, 1024, 0);
            vtb_k<<<dim3(8, 16, Bc * 4), 256, 0, stream>>>(qkvb, Vt);
            bgemm_k<<<dim3(4, 4, Bc * 4), 256, 0, stream>>>(
                qkvb, 3072, (size_t)512 * 3072, 256,
                qkvb + 1024, 3072, (size_t)512 * 3072, 256,
                scr, nullptr, 512, (size_t)4 * 512 * 512, 512 * 512, 256);
            softmax_k<<<R, 256, 0, stream>>>(scr, Pb);
            bgemm_k<<<dim3(2, 4, Bc * 4), 256, 0, stream>>>(
                Pb, 512, (size_t)4 * 512 * 512, 512 * 512,
                Vt, 512, (size_t)4 * 256 * 512, 256 * 512,
                nullptr, qkvb, 3072, (size_t)512 * 3072, 256, 512);
            // wo-out -> bf16 only (Pb), residual-LN reads bf16
            MG(qkvb, 3072, woT[l], t_bo + (size_t)l*1024, nullptr, Pb, 1024, 1024, 1024, 0);
            addlnb_k<<<R, 256, 0, stream>>>(h, hb, Pb,
                                            t_ln1g + (size_t)l*Dz, t_ln1b + (size_t)l*Dz);
            MG(hb, 1024, w1T[l], t_b1 + (size_t)l*FFz, nullptr, qkvb, 2048, 2048, 1024, 1);
            MG(qkvb, 2048, w2T[l], t_b2 + (size_t)l*Dz, nullptr, Pb, 1024, 1024, 2048, 0);
            addlnb_k<<<R, 256, 0, stream>>>(h, hb, Pb,
                                            t_ln2g + (size_t)l*Dz, t_ln2b + (size_t)l*Dz);
        }

        // tail buffers sublet scr (f32) and Pb (bf16)
        float*    shared  = scr;                       // [R,512]
        float*    proj    = scr + (size_t)R * 512;     // [R,256]
        float*    kvb     = scr + (size_t)R * 768;     // [R,512] combined k|v
        float*    fin     = scr + (size_t)R * 1280;    // [R,512]
        ushort_t* sharedb = Pb;                        // [R,512]
        ushort_t* projb   = Pb + (size_t)R * 512;      // [R,256]
        ushort_t* fb      = Pb + (size_t)R * 768;      // [R,256]
        ushort_t* fpb     = qkvb;                      // [R,1024]

        // 3. shared = relu(BN1(h @ sb_w + sb_b))  (dual out)
        MG(hb, 1024, sbT, sb_b, shared, sharedb, 512, 512, 1024, 2, bn1_g, bn1_b, bn1_m, bn1_v);
        // 4. scores, top-k, agg, classifier
        rowdot_k<<<R, 256, 0, stream>>>(shared, dt_w, dt_b, scores + (size_t)b0 * Tz);
        topk_k<<<Bc, 256, 0, stream>>>(scores + (size_t)b0 * Tz, tkidx);
        agg_k<<<Bc, 256, 0, stream>>>(shared, tkidx, aggbuf);
        cls_k<<<Bc, 256, 0, stream>>>(aggbuf, cc_w1, cc_b1, bn2_g, bn2_b, bn2_m, bn2_v,
                                      cc_w2, cc_b2, ce, ca_wqkv, ca_bqkv,
                                      out + BT + (size_t)b0 * KC, qxbuf);
        // 5. proj (dual), combined cross k|v
        MG(sharedb, 512, kpT, kp_b, proj, projb, 256, 256, 512, 0);
        MG(projb, 256, kvT, ca_bqkv + Ez, kvb, nullptr, 512, 512, 256, 0);
        // 6. cross attention (+wo fused) + final fuse
        xattn_k<<<Bc, 256, 0, stream>>>(qxbuf, kvb, ca_wo, ca_bo, ctx2buf);
        addctx_k<<<(R * Ez) / 256, 256, 0, stream>>>(proj, ctx2buf, fb);
        // 7. fp_out (bf16) -> fin (BN+relu fp32) -> seg
        MG(fb, 256, fpT, fp_b, nullptr, fpb, 1024, 1024, 256, 0);
        MG(fpb, 1024, sbT, sb_b, fin, nullptr, 512, 512, 1024, 2, bn1_g, bn1_b, bn1_m, bn1_v);
        rowdot_k<<<R, 256, 0, stream>>>(fin, df_w, df_b, out + (size_t)b0 * Tz);
    }
}

// Round 9
// 1803.768 us; speedup vs baseline: 1.1762x; 1.1053x over previous
//
#include <hip/hip_runtime.h>
#include <math.h>

#define Bz 32
#define Tz 512
#define Dz 1024
#define Pz 512
#define Ez 256
#define KC 14
#define NHz 4
#define Lz 2
#define FFz 2048
#define TOPKz 7
#define EPSz 1e-5f
#define BT (Bz*Tz)

typedef unsigned short ushort_t;
typedef __attribute__((ext_vector_type(8))) short short8;
typedef __attribute__((ext_vector_type(4))) float f32x4;

__device__ __forceinline__ ushort_t f2bf(float f) {
    union { float f; unsigned int u; } x; x.f = f;
    unsigned int r = x.u + 0x7fffu + ((x.u >> 16) & 1u);   // RNE (finite inputs)
    return (ushort_t)(r >> 16);
}
__device__ __forceinline__ float bf2f(ushort_t h) {
    union { unsigned int u; float f; } x; x.u = ((unsigned int)h) << 16; return x.f;
}

// ---------------- 128x128 bf16 MFMA GEMM (m97 structure): C = A @ W^T (+bias, epi) -------------
// Dual outputs: Cf (fp32) and/or Ch (bf16), either may be null. epi: 0=none,1=relu,2=BN+relu
__global__ __launch_bounds__(256) void mgemm_k(
    const ushort_t* __restrict__ A, int lda,
    const ushort_t* __restrict__ Wt,
    const float* __restrict__ bias,
    float* __restrict__ Cf, ushort_t* __restrict__ Ch, int ldc,
    int Kd, int epi,
    const float* __restrict__ bng, const float* __restrict__ bnb,
    const float* __restrict__ bnm, const float* __restrict__ bnv)
{
    __shared__ __align__(16) ushort_t As[128 * 32];
    __shared__ __align__(16) ushort_t Bs[128 * 32];
    const int tid = threadIdx.x;
    const int lane = tid & 63, wid = tid >> 6;
    const int row0 = blockIdx.y * 128, col0 = blockIdx.x * 128;
    const int wrow = (wid >> 1) * 64, wcol = (wid & 1) * 64;
    const int srow = (lane >> 2);
    const int skoff = (lane & 3) * 8;

    f32x4 acc[4][4];
    const f32x4 zr = {0.f, 0.f, 0.f, 0.f};
    #pragma unroll
    for (int m = 0; m < 4; m++)
        #pragma unroll
        for (int n = 0; n < 4; n++) acc[m][n] = zr;

    for (int k0 = 0; k0 < Kd; k0 += 32) {
        #pragma unroll
        for (int j = 0; j < 2; j++) {
            const int r = wid * 32 + j * 16;
            const ushort_t* ga = A + (size_t)(row0 + r + srow) * lda + k0 + skoff;
            __builtin_amdgcn_global_load_lds(
                (const __attribute__((address_space(1))) unsigned int*)ga,
                (__attribute__((address_space(3))) unsigned int*)(As + r * 32), 16, 0, 0);
            const ushort_t* gb = Wt + (size_t)(col0 + r + srow) * Kd + k0 + skoff;
            __builtin_amdgcn_global_load_lds(
                (const __attribute__((address_space(1))) unsigned int*)gb,
                (__attribute__((address_space(3))) unsigned int*)(Bs + r * 32), 16, 0, 0);
        }
        __syncthreads();
        short8 af[4], bf[4];
        #pragma unroll
        for (int m = 0; m < 4; m++)
            af[m] = *(const short8*)(As + (wrow + m * 16 + (lane & 15)) * 32 + (lane >> 4) * 8);
        #pragma unroll
        for (int n = 0; n < 4; n++)
            bf[n] = *(const short8*)(Bs + (wcol + n * 16 + (lane & 15)) * 32 + (lane >> 4) * 8);
        #pragma unroll
        for (int m = 0; m < 4; m++)
            #pragma unroll
            for (int n = 0; n < 4; n++)
                acc[m][n] = __builtin_amdgcn_mfma_f32_16x16x32_bf16(af[m], bf[n], acc[m][n], 0, 0, 0);
        __syncthreads();
    }

    #pragma unroll
    for (int n = 0; n < 4; n++) {
        const int ccol = col0 + wcol + n * 16 + (lane & 15);
        const float bb = bias[ccol];
        float bsc = 1.f, bsh = 0.f;
        if (epi == 2) {
            bsc = rsqrtf(bnv[ccol] + EPSz) * bng[ccol];
            bsh = bnb[ccol] - bnm[ccol] * bsc;
        }
        #pragma unroll
        for (int m = 0; m < 4; m++) {
            #pragma unroll
            for (int r = 0; r < 4; r++) {
                const int crow = row0 + wrow + m * 16 + (lane >> 4) * 4 + r;
                float y = acc[m][n][r] + bb;
                if (epi == 2) y = y * bsc + bsh;
                if (epi >= 1) y = fmaxf(y, 0.f);
                if (Cf) Cf[(size_t)crow * ldc + ccol] = y;
                if (Ch) Ch[(size_t)crow * ldc + ccol] = f2bf(y);
            }
        }
    }
}

// ---------------- batched bf16 MFMA GEMM over z=(batch,head): fp32 OR bf16 out -----------------
__global__ __launch_bounds__(256) void bgemm_k(
    const ushort_t* __restrict__ A0, int lda, size_t Abz, int Ahz,
    const ushort_t* __restrict__ W0, int ldw, size_t Wbz, int Whz,
    float* __restrict__ Cf0, ushort_t* __restrict__ Ch0, int ldc, size_t Cbz, int Chz, int Kd)
{
    const int z = blockIdx.z, bl = z >> 2, hh = z & 3;
    const ushort_t* A = A0 + (size_t)bl * Abz + (size_t)hh * Ahz;
    const ushort_t* W = W0 + (size_t)bl * Wbz + (size_t)hh * Whz;

    __shared__ __align__(16) ushort_t As[128 * 32];
    __shared__ __align__(16) ushort_t Bs[128 * 32];
    const int tid = threadIdx.x;
    const int lane = tid & 63, wid = tid >> 6;
    const int row0 = blockIdx.y * 128, col0 = blockIdx.x * 128;
    const int wrow = (wid >> 1) * 64, wcol = (wid & 1) * 64;
    const int srow = (lane >> 2);
    const int skoff = (lane & 3) * 8;

    f32x4 acc[4][4];
    const f32x4 zr = {0.f, 0.f, 0.f, 0.f};
    #pragma unroll
    for (int m = 0; m < 4; m++)
        #pragma unroll
        for (int n = 0; n < 4; n++) acc[m][n] = zr;

    for (int k0 = 0; k0 < Kd; k0 += 32) {
        #pragma unroll
        for (int j = 0; j < 2; j++) {
            const int r = wid * 32 + j * 16;
            const ushort_t* ga = A + (size_t)(row0 + r + srow) * lda + k0 + skoff;
            __builtin_amdgcn_global_load_lds(
                (const __attribute__((address_space(1))) unsigned int*)ga,
                (__attribute__((address_space(3))) unsigned int*)(As + r * 32), 16, 0, 0);
            const ushort_t* gb = W + (size_t)(col0 + r + srow) * ldw + k0 + skoff;
            __builtin_amdgcn_global_load_lds(
                (const __attribute__((address_space(1))) unsigned int*)gb,
                (__attribute__((address_space(3))) unsigned int*)(Bs + r * 32), 16, 0, 0);
        }
        __syncthreads();
        short8 af[4], bf[4];
        #pragma unroll
        for (int m = 0; m < 4; m++)
            af[m] = *(const short8*)(As + (wrow + m * 16 + (lane & 15)) * 32 + (lane >> 4) * 8);
        #pragma unroll
        for (int n = 0; n < 4; n++)
            bf[n] = *(const short8*)(Bs + (wcol + n * 16 + (lane & 15)) * 32 + (lane >> 4) * 8);
        #pragma unroll
        for (int m = 0; m < 4; m++)
            #pragma unroll
            for (int n = 0; n < 4; n++)
                acc[m][n] = __builtin_amdgcn_mfma_f32_16x16x32_bf16(af[m], bf[n], acc[m][n], 0, 0, 0);
        __syncthreads();
    }

    #pragma unroll
    for (int n = 0; n < 4; n++) {
        const int ccol = col0 + wcol + n * 16 + (lane & 15);
        #pragma unroll
        for (int m = 0; m < 4; m++) {
            #pragma unroll
            for (int r = 0; r < 4; r++) {
                const int crow = row0 + wrow + m * 16 + (lane >> 4) * 4 + r;
                const float y = acc[m][n][r];
                if (Cf0) (Cf0 + (size_t)bl * Cbz + (size_t)hh * Chz)[(size_t)crow * ldc + ccol] = y;
                if (Ch0) (Ch0 + (size_t)bl * Cbz + (size_t)hh * Chz)[(size_t)crow * ldc + ccol] = f2bf(y);
            }
        }
    }
}

// ------------- in-place softmax over bf16 S rows (scale 1/16) -> normalized bf16 P -------------
__global__ __launch_bounds__(256) void softmax_k(ushort_t* __restrict__ SP)
{
    const int row = blockIdx.x * 4 + (threadIdx.x >> 6);
    const int lane = threadIdx.x & 63;
    ushort_t* rp = SP + (size_t)row * 512 + lane * 8;
    union { ushort_t h[8]; uint4 u; } in;
    in.u = *(const uint4*)rp;
    float v[8];
    #pragma unroll
    for (int i = 0; i < 8; i++) v[i] = bf2f(in.h[i]) * 0.0625f;
    float m = v[0];
    #pragma unroll
    for (int i = 1; i < 8; i++) m = fmaxf(m, v[i]);
    #pragma unroll
    for (int off = 32; off > 0; off >>= 1) m = fmaxf(m, __shfl_xor(m, off));
    float s = 0.f;
    #pragma unroll
    for (int i = 0; i < 8; i++) { v[i] = expf(v[i] - m); s += v[i]; }
    #pragma unroll
    for (int off = 32; off > 0; off >>= 1) s += __shfl_xor(s, off);
    const float inv = 1.f / s;
    union { ushort_t h[8]; uint4 u; } pk;
    #pragma unroll
    for (int i = 0; i < 8; i++) pk.h[i] = f2bf(v[i] * inv);
    *(uint4*)rp = pk.u;
}

// ------------- z-batched bf16 transpose: V[kv][d] (qkvb v-slots) -> Vt[d][kv] ------------------
__global__ __launch_bounds__(256) void vtb_k(
    const ushort_t* __restrict__ qkvb, ushort_t* __restrict__ Vt)
{
    const int z = blockIdx.z, bl = z >> 2, hh = z & 3;
    const ushort_t* src = qkvb + (size_t)bl * 512 * 3072 + 2048 + hh * 256;
    ushort_t* dst = Vt + (size_t)z * 256 * 512;
    __shared__ ushort_t t[32][33];
    const int tx = threadIdx.x & 31, ty = threadIdx.x >> 5;
    const int gx = blockIdx.x * 32;   // d
    const int gy = blockIdx.y * 32;   // kv
    #pragma unroll
    for (int i = 0; i < 4; i++) {
        const int row = ty + i * 8;
        t[row][tx] = src[(size_t)(gy + row) * 3072 + gx + tx];
    }
    __syncthreads();
    #pragma unroll
    for (int i = 0; i < 4; i++) {
        const int nr = ty + i * 8;
        dst[(size_t)(gx + nr) * 512 + gy + tx] = t[tx][nr];
    }
}

// ------------- merged weight transpose+cast: 13 jobs, one launch -------------------------------
struct WtJobs {
    const float* src[13];
    ushort_t*    dst[13];
    int ld[13];
    int Kd[13];
    int nx[13];
    int base[14];
};

__global__ __launch_bounds__(256) void wtall_k(WtJobs J)
{
    const int bid = blockIdx.x;
    int j = 0;
    #pragma unroll
    for (int i = 0; i < 12; i++) if (bid >= J.base[i + 1]) j = i + 1;
    const int local = bid - J.base[j];
    const int bx = local % J.nx[j], by = local / J.nx[j];
    const float* src = J.src[j];
    ushort_t* dst = J.dst[j];
    const int ld = J.ld[j], Kd = J.Kd[j];

    __shared__ float t[32][33];
    const int tx = threadIdx.x & 31, ty = threadIdx.x >> 5;
    const int gx = bx * 32;
    const int gy = by * 32;
    #pragma unroll
    for (int i = 0; i < 4; i++) {
        const int row = ty + i * 8;
        t[row][tx] = src[(size_t)(gy + row) * ld + gx + tx];
    }
    __syncthreads();
    #pragma unroll
    for (int i = 0; i < 4; i++) {
        const int nr = ty + i * 8;
        dst[(size_t)(gx + nr) * Kd + gy + tx] = f2bf(t[tx][nr]);
    }
}

// ------------- fused shift-predictor + TSM shift (bf16 out) ------------------------------------
__global__ __launch_bounds__(256) void predshift_k(
    const float* __restrict__ x, const float* __restrict__ pred_w,
    const float* __restrict__ pred_b, ushort_t* __restrict__ hb)
{
    const int row = blockIdx.x, tid = threadIdx.x;
    const size_t base = (size_t)row * Dz;
    float s = 0.f;
    #pragma unroll
    for (int i = 0; i < 4; i++) {
        int c = tid + i * 256;
        s += x[base + c] * pred_w[c];
    }
    __shared__ float red[256];
    __shared__ int sns;
    red[tid] = s; __syncthreads();
    for (int off = 128; off > 0; off >>= 1) {
        if (tid < off) red[tid] += red[tid + off];
        __syncthreads();
    }
    if (tid == 0) {
        float sg = 1.f / (1.f + expf(-(red[0] + pred_b[0])));
        sns = (int)(sg * (float)(Dz / 2));
    }
    __syncthreads();
    const int sn = sns;
    const int t = row & (Tz - 1);
    #pragma unroll
    for (int i = 0; i < 4; i++) {
        const int c = tid + i * 256;
        const size_t idx = base + c;
        float v;
        if (c < sn)          v = (t > 0)      ? x[idx - Dz] : 0.f;
        else if (c < 2 * sn) v = (t < Tz - 1) ? x[idx + Dz] : 0.f;
        else                 v = x[idx];
        hb[idx] = f2bf(v);
    }
}

// ------------- hb = bf16(LN(hb + r)) — bf16 residual stream ------------------------------------
__global__ __launch_bounds__(256) void addlnb_k(
    ushort_t* __restrict__ hb, const ushort_t* __restrict__ r,
    const float* __restrict__ g, const float* __restrict__ b)
{
    const int row = blockIdx.x, tid = threadIdx.x;
    const size_t base = (size_t)row * Dz;
    float x[4]; float s = 0.f, sq = 0.f;
    #pragma unroll
    for (int i = 0; i < 4; i++) {
        const int c = tid + i * 256;
        x[i] = bf2f(hb[base + c]) + bf2f(r[base + c]);
        s += x[i]; sq += x[i] * x[i];
    }
    __shared__ float rs[256], rq[256];
    rs[tid] = s; rq[tid] = sq; __syncthreads();
    for (int off = 128; off > 0; off >>= 1) {
        if (tid < off) { rs[tid] += rs[tid + off]; rq[tid] += rq[tid + off]; }
        __syncthreads();
    }
    float mean = rs[0] * (1.f / Dz);
    float var = rq[0] * (1.f / Dz) - mean * mean;
    float inv = rsqrtf(var + EPSz);
    #pragma unroll
    for (int i = 0; i < 4; i++) {
        int c = tid + i * 256;
        float y = (x[i] - mean) * inv * g[c] + b[c];
        hb[base + c] = f2bf(y);
    }
}

// ------------- rowdot: out[row] = dot(in[row,:512], w) + b -------------------------------------
__global__ __launch_bounds__(256) void rowdot_k(
    const float* __restrict__ in, const float* __restrict__ w,
    const float* __restrict__ bptr, float* __restrict__ outf)
{
    const int row = blockIdx.x, tid = threadIdx.x;
    const float* r = in + (size_t)row * Pz;
    float s = 0.f;
    #pragma unroll
    for (int c = tid; c < Pz; c += 256) s += r[c] * w[c];
    __shared__ float red[256];
    red[tid] = s; __syncthreads();
    for (int off = 128; off > 0; off >>= 1) {
        if (tid < off) red[tid] += red[tid + off];
        __syncthreads();
    }
    if (tid == 0) outf[row] = red[0] + bptr[0];
}

// ------------- top-k (7 of 512) per (chunk-local) batch row ------------------------------------
__global__ __launch_bounds__(256) void topk_k(const float* __restrict__ scores, int* __restrict__ idx)
{
    const int b = blockIdx.x, tid = threadIdx.x;
    __shared__ float sv[Tz];
    __shared__ float rv[256]; __shared__ int ri[256];
    sv[tid] = scores[b * Tz + tid];
    sv[tid + 256] = scores[b * Tz + tid + 256];
    __syncthreads();
    for (int it = 0; it < TOPKz; it++) {
        float v0 = sv[tid]; int i0 = tid;
        float v1 = sv[tid + 256];
        if (v1 > v0) { v0 = v1; i0 = tid + 256; }
        rv[tid] = v0; ri[tid] = i0; __syncthreads();
        for (int off = 128; off > 0; off >>= 1) {
            if (tid < off) {
                if (rv[tid + off] > rv[tid] ||
                    (rv[tid + off] == rv[tid] && ri[tid + off] < ri[tid])) {
                    rv[tid] = rv[tid + off]; ri[tid] = ri[tid + off];
                }
            }
            __syncthreads();
        }
        if (tid == 0) { idx[b * TOPKz + it] = ri[0]; sv[ri[0]] = -INFINITY; }
        __syncthreads();
    }
}

// ------------- agg = mean of top-k rows of shared ---------------------------------------------
__global__ __launch_bounds__(256) void agg_k(
    const float* __restrict__ sh, const int* __restrict__ idx, float* __restrict__ agg)
{
    const int b = blockIdx.x, tid = threadIdx.x;
    for (int p = tid; p < Pz; p += 256) {
        float s = 0.f;
        #pragma unroll
        for (int j = 0; j < TOPKz; j++) {
            int t = idx[b * TOPKz + j];
            s += sh[((size_t)b * Tz + t) * Pz + p];
        }
        agg[b * Pz + p] = s * (1.f / TOPKz);
    }
}

// ------------- fused classifier: c1 -> logits -> softmax -> cat_emb -> cross-q -----------------
__global__ __launch_bounds__(256) void cls_k(
    const float* __restrict__ agg,
    const float* __restrict__ cc_w1, const float* __restrict__ cc_b1,
    const float* __restrict__ g2, const float* __restrict__ b2,
    const float* __restrict__ m2, const float* __restrict__ v2,
    const float* __restrict__ cc_w2, const float* __restrict__ cc_b2,
    const float* __restrict__ ce,
    const float* __restrict__ ca_wqkv, const float* __restrict__ ca_bqkv,
    float* __restrict__ logits_out, float* __restrict__ qx)
{
    const int b = blockIdx.x, tid = threadIdx.x;
    __shared__ float ag[Pz], c1s[256], sm[16], cemb[256];
    ag[tid] = agg[b * Pz + tid];
    ag[tid + 256] = agg[b * Pz + tid + 256];
    __syncthreads();
    float s = 0.f;
    for (int p = 0; p < Pz; p++) s += ag[p] * cc_w1[p * 256 + tid];
    s += cc_b1[tid];
    s = (s - m2[tid]) * rsqrtf(v2[tid] + EPSz) * g2[tid] + b2[tid];
    s = fmaxf(s, 0.f);
    c1s[tid] = s;
    __syncthreads();
    if (tid < KC) {
        float l = 0.f;
        for (int e = 0; e < 256; e++) l += c1s[e] * cc_w2[e * KC + tid];
        l += cc_b2[tid];
        sm[tid] = l;
        logits_out[b * KC + tid] = l;
    }
    __syncthreads();
    if (tid == 0) {
        float mx = sm[0];
        for (int k = 1; k < KC; k++) mx = fmaxf(mx, sm[k]);
        float su = 0.f;
        for (int k = 0; k < KC; k++) { sm[k] = expf(sm[k] - mx); su += sm[k]; }
        float inv = 1.f / su;
        for (int k = 0; k < KC; k++) sm[k] *= inv;
    }
    __syncthreads();
    float cesum = 0.f;
    #pragma unroll
    for (int k = 0; k < KC; k++) cesum += sm[k] * ce[k * 256 + tid];
    cemb[tid] = cesum; __syncthreads();
    float q = 0.f;
    for (int i = 0; i < 256; i++) q += cemb[i] * ca_wqkv[i * 768 + tid];
    qx[b * 256 + tid] = q + ca_bqkv[tid];
}

// ------------- cross-attention (Tq=1) on combined kv[R,512] + fused wo projection --------------
__global__ __launch_bounds__(256) void xattn_k(
    const float* __restrict__ qx, const float* __restrict__ kv,
    const float* __restrict__ ca_wo, const float* __restrict__ ca_bo,
    float* __restrict__ ctx2)
{
    const int b = blockIdx.x, tid = threadIdx.x;
    __shared__ float q4[256];
    __shared__ float sc[NHz][Tz];
    __shared__ float cx[256];
    q4[tid] = qx[b * 256 + tid];
    __syncthreads();
    for (int si = tid; si < NHz * Tz; si += 256) {
        int hh = si >> 9, t = si & (Tz - 1);
        const float* kr = kv + ((size_t)b * Tz + t) * 512 + hh * 64;
        const float* qr = q4 + hh * 64;
        float s = 0.f;
        #pragma unroll 8
        for (int d = 0; d < 64; d++) s += qr[d] * kr[d];
        sc[hh][t] = s * 0.125f;
    }
    __syncthreads();
    const int hh = tid >> 6, lane = tid & 63;
    float mx = -INFINITY;
    for (int t = lane; t < Tz; t += 64) mx = fmaxf(mx, sc[hh][t]);
    for (int off = 32; off > 0; off >>= 1) mx = fmaxf(mx, __shfl_xor(mx, off));
    float su = 0.f;
    for (int t = lane; t < Tz; t += 64) { float e = expf(sc[hh][t] - mx); sc[hh][t] = e; su += e; }
    for (int off = 32; off > 0; off >>= 1) su += __shfl_xor(su, off);
    float inv = 1.f / su;
    __syncthreads();
    float acc = 0.f;
    for (int t = 0; t < Tz; t++) acc += sc[hh][t] * kv[((size_t)b * Tz + t) * 512 + 256 + tid];
    cx[tid] = acc * inv;
    __syncthreads();
    float s2 = 0.f;
    for (int i = 0; i < 256; i++) s2 += cx[i] * ca_wo[i * 256 + tid];
    ctx2[b * 256 + tid] = s2 + ca_bo[tid];
}

// ------------- fb = bf16(proj + ctx2) (broadcast over T) ---------------------------------------
__global__ __launch_bounds__(256) void addctx_k(
    const float* __restrict__ proj, const float* __restrict__ ctx2, ushort_t* __restrict__ fb)
{
    size_t idx = (size_t)blockIdx.x * 256 + threadIdx.x;   // over R*E
    int e = (int)(idx & 255);
    int b = (int)(idx >> 17);                              // T*E = 2^17
    fb[idx] = f2bf(proj[idx] + ctx2[b * 256 + e]);
}

// ==============================================================================================
extern "C" void kernel_launch(void* const* d_in, const int* in_sizes, int n_in,
                              void* d_out, int out_size, void* d_ws, size_t ws_size,
                              hipStream_t stream)
{
    const float* x       = (const float*)d_in[0];
    const float* pred_w  = (const float*)d_in[1];
    const float* pred_b  = (const float*)d_in[2];
    const float* t_wqkv  = (const float*)d_in[3];
    const float* t_bqkv  = (const float*)d_in[4];
    const float* t_wo    = (const float*)d_in[5];
    const float* t_bo    = (const float*)d_in[6];
    const float* t_ln1g  = (const float*)d_in[7];
    const float* t_ln1b  = (const float*)d_in[8];
    const float* t_w1    = (const float*)d_in[9];
    const float* t_b1    = (const float*)d_in[10];
    const float* t_w2    = (const float*)d_in[11];
    const float* t_b2    = (const float*)d_in[12];
    const float* t_ln2g  = (const float*)d_in[13];
    const float* t_ln2b  = (const float*)d_in[14];
    const float* sb_w    = (const float*)d_in[15];
    const float* sb_b    = (const float*)d_in[16];
    const float* bn1_g   = (const float*)d_in[17];
    const float* bn1_b   = (const float*)d_in[18];
    const float* bn1_m   = (const float*)d_in[19];
    const float* bn1_v   = (const float*)d_in[20];
    const float* dt_w    = (const float*)d_in[21];
    const float* dt_b    = (const float*)d_in[22];
    const float* cc_w1   = (const float*)d_in[23];
    const float* cc_b1   = (const float*)d_in[24];
    const float* bn2_g   = (const float*)d_in[25];
    const float* bn2_b   = (const float*)d_in[26];
    const float* bn2_m   = (const float*)d_in[27];
    const float* bn2_v   = (const float*)d_in[28];
    const float* cc_w2   = (const float*)d_in[29];
    const float* cc_b2   = (const float*)d_in[30];
    const float* ce      = (const float*)d_in[31];
    const float* kp_w    = (const float*)d_in[32];
    const float* kp_b    = (const float*)d_in[33];
    const float* ca_wqkv = (const float*)d_in[34];
    const float* ca_bqkv = (const float*)d_in[35];
    const float* ca_wo   = (const float*)d_in[36];
    const float* ca_bo   = (const float*)d_in[37];
    const float* fp_w    = (const float*)d_in[38];
    const float* fp_b    = (const float*)d_in[39];
    const float* df_w    = (const float*)d_in[40];
    const float* df_b    = (const float*)d_in[41];

    float* out = (float*)d_out;

    char* wp = (char*)d_ws;
    auto alloc = [&](size_t bytes) -> char* {
        char* r = wp; wp += (bytes + 255) & ~(size_t)255; return r;
    };
    float* scores  = (float*)alloc(BT * 4);
    int*   tkidx   = (int*)alloc(256 * 4);
    float* aggbuf  = (float*)alloc((size_t)Bz * Pz * 4);
    float* qxbuf   = (float*)alloc((size_t)Bz * Ez * 4);
    float* ctx2buf = (float*)alloc((size_t)Bz * Ez * 4);

    const size_t WT_TOTAL = 2*(size_t)3072*1024 + 2*(size_t)1024*1024 + 2*(size_t)2048*1024
                          + 2*(size_t)1024*2048 + (size_t)512*1024 + (size_t)256*512
                          + 2*(size_t)256*256 + (size_t)1024*256;
    ushort_t* wtb = (ushort_t*)alloc(WT_TOTAL * 2);
    size_t woff = 0;
    auto nxt = [&](size_t n) -> ushort_t* { ushort_t* r = wtb + woff; woff += n; return r; };
    ushort_t* qkvT[2] = { nxt((size_t)3072*1024), nxt((size_t)3072*1024) };
    ushort_t* woT[2]  = { nxt((size_t)1024*1024), nxt((size_t)1024*1024) };
    ushort_t* w1T[2]  = { nxt((size_t)2048*1024), nxt((size_t)2048*1024) };
    ushort_t* w2T[2]  = { nxt((size_t)1024*2048), nxt((size_t)1024*2048) };
    ushort_t* sbT  = nxt((size_t)512*1024);
    ushort_t* kpT  = nxt((size_t)256*512);
    ushort_t* kvT  = nxt((size_t)512*256);   // combined cross k|v weight [512][256]
    ushort_t* fpT  = nxt((size_t)1024*256);

    // per-row bytes: hb 2048 + qkvb 6144 + scr 8192 + Pb 4096 + Vt 2048 = 22528
    size_t fixedB = (size_t)(wp - (char*)d_ws);
    int Bc = Bz;
    while (Bc > 1 && fixedB + (size_t)Bc * Tz * 22528 + 1048576 > ws_size) Bc >>= 1;
    const int Rmax = Bc * Tz;
    ushort_t* hb   = (ushort_t*)alloc((size_t)Rmax * 1024 * 2);
    ushort_t* qkvb = (ushort_t*)alloc((size_t)Rmax * 3072 * 2);
    float*    scr  = (float*)alloc((size_t)Rmax * 2048 * 4);    // tail f32
    ushort_t* Pb   = (ushort_t*)alloc((size_t)Rmax * 2048 * 2); // S/P / residuals / tail bf16
    ushort_t* Vt   = (ushort_t*)alloc((size_t)Rmax * 1024 * 2);

    // ---- one-time weight transpose+cast: single merged launch ----
    {
        WtJobs J;
        const float* srcs[13] = { t_wqkv, t_wqkv + (size_t)1024*3072, t_wo, t_wo + (size_t)1024*1024,
                                  t_w1, t_w1 + (size_t)1024*2048, t_w2, t_w2 + (size_t)2048*1024,
                                  sb_w, kp_w, ca_wqkv + Ez, ca_wqkv + 2*Ez, fp_w };
        ushort_t* dsts[13] = { qkvT[0], qkvT[1], woT[0], woT[1], w1T[0], w1T[1], w2T[0], w2T[1],
                               sbT, kpT, kvT, kvT + (size_t)256*256, fpT };
        const int lds_[13] = { 3072, 3072, 1024, 1024, 2048, 2048, 1024, 1024, 512, 256, 768, 768, 1024 };
        const int kds_[13] = { 1024, 1024, 1024, 1024, 1024, 1024, 2048, 2048, 1024, 512, 256, 256, 256 };
        const int nxs_[13] = { 96, 96, 32, 32, 64, 64, 32, 32, 16, 8, 8, 8, 32 };
        const int nys_[13] = { 32, 32, 32, 32, 32, 32, 64, 64, 32, 16, 8, 8, 8 };
        int acc = 0;
        for (int i = 0; i < 13; i++) {
            J.src[i] = srcs[i]; J.dst[i] = dsts[i];
            J.ld[i] = lds_[i]; J.Kd[i] = kds_[i]; J.nx[i] = nxs_[i];
            J.base[i] = acc; acc += nxs_[i] * nys_[i];
        }
        J.base[13] = acc;
        wtall_k<<<acc, 256, 0, stream>>>(J);
    }

    for (int b0 = 0; b0 < Bz; b0 += Bc) {
        const int R = Bc * Tz;
        const float* xc = x + (size_t)b0 * Tz * Dz;

        auto MG = [&](const ushort_t* Ain, int lda, const ushort_t* Wt_, const float* bias,
                      float* Cf, ushort_t* Ch, int ldc, int N, int Kd, int epi,
                      const float* g = nullptr, const float* bb = nullptr,
                      const float* m = nullptr, const float* v = nullptr) {
            mgemm_k<<<dim3(N/128, R/128), 256, 0, stream>>>(
                Ain, lda, Wt_, bias, Cf, Ch, ldc, Kd, epi, g, bb, m, v);
        };

        // 1. fused shift-predictor + TSM -> hb (bf16 residual stream)
        predshift_k<<<R, 256, 0, stream>>>(xc, pred_w, pred_b, hb);

        // 2. transformer layers
        for (int l = 0; l < Lz; l++) {
            MG(hb, 1024, qkvT[l], t_bqkv + (size_t)l*3072, nullptr, qkvb, 3072, 3072, 1024, 0);
            vtb_k<<<dim3(8, 16, Bc * 4), 256, 0, stream>>>(qkvb, Vt);
            // S = QK^T -> bf16 into Pb
            bgemm_k<<<dim3(4, 4, Bc * 4), 256, 0, stream>>>(
                qkvb, 3072, (size_t)512 * 3072, 256,
                qkvb + 1024, 3072, (size_t)512 * 3072, 256,
                nullptr, Pb, 512, (size_t)4 * 512 * 512, 512 * 512, 256);
            softmax_k<<<R, 256, 0, stream>>>(Pb);               // in-place
            bgemm_k<<<dim3(2, 4, Bc * 4), 256, 0, stream>>>(
                Pb, 512, (size_t)4 * 512 * 512, 512 * 512,
                Vt, 512, (size_t)4 * 256 * 512, 256 * 512,
                nullptr, qkvb, 3072, (size_t)512 * 3072, 256, 512);
            // wo-out -> bf16 (Pb), residual-LN on bf16
            MG(qkvb, 3072, woT[l], t_bo + (size_t)l*1024, nullptr, Pb, 1024, 1024, 1024, 0);
            addlnb_k<<<R, 256, 0, stream>>>(hb, Pb,
                                            t_ln1g + (size_t)l*Dz, t_ln1b + (size_t)l*Dz);
            MG(hb, 1024, w1T[l], t_b1 + (size_t)l*FFz, nullptr, qkvb, 2048, 2048, 1024, 1);
            MG(qkvb, 2048, w2T[l], t_b2 + (size_t)l*Dz, nullptr, Pb, 1024, 1024, 2048, 0);
            addlnb_k<<<R, 256, 0, stream>>>(hb, Pb,
                                            t_ln2g + (size_t)l*Dz, t_ln2b + (size_t)l*Dz);
        }

        // tail buffers sublet scr (f32) and Pb (bf16)
        float*    shared  = scr;                       // [R,512]
        float*    proj    = scr + (size_t)R * 512;     // [R,256]
        float*    kvb     = scr + (size_t)R * 768;     // [R,512] combined k|v
        float*    fin     = scr + (size_t)R * 1280;    // [R,512]
        ushort_t* sharedb = Pb;                        // [R,512]
        ushort_t* projb   = Pb + (size_t)R * 512;      // [R,256]
        ushort_t* fb      = Pb + (size_t)R * 768;      // [R,256]
        ushort_t* fpb     = qkvb;                      // [R,1024]

        // 3. shared = relu(BN1(h @ sb_w + sb_b))  (dual out)
        MG(hb, 1024, sbT, sb_b, shared, sharedb, 512, 512, 1024, 2, bn1_g, bn1_b, bn1_m, bn1_v);
        // 4. scores, top-k, agg, classifier
        rowdot_k<<<R, 256, 0, stream>>>(shared, dt_w, dt_b, scores + (size_t)b0 * Tz);
        topk_k<<<Bc, 256, 0, stream>>>(scores + (size_t)b0 * Tz, tkidx);
        agg_k<<<Bc, 256, 0, stream>>>(shared, tkidx, aggbuf);
        cls_k<<<Bc, 256, 0, stream>>>(aggbuf, cc_w1, cc_b1, bn2_g, bn2_b, bn2_m, bn2_v,
                                      cc_w2, cc_b2, ce, ca_wqkv, ca_bqkv,
                                      out + BT + (size_t)b0 * KC, qxbuf);
        // 5. proj (dual), combined cross k|v
        MG(sharedb, 512, kpT, kp_b, proj, projb, 256, 256, 512, 0);
        MG(projb, 256, kvT, ca_bqkv + Ez, kvb, nullptr, 512, 512, 256, 0);
        // 6. cross attention (+wo fused) + final fuse
        xattn_k<<<Bc, 256, 0, stream>>>(qxbuf, kvb, ca_wo, ca_bo, ctx2buf);
        addctx_k<<<(R * Ez) / 256, 256, 0, stream>>>(proj, ctx2buf, fb);
        // 7. fp_out (bf16) -> fin (BN+relu fp32) -> seg
        MG(fb, 256, fpT, fp_b, nullptr, fpb, 1024, 1024, 256, 0);
        MG(fpb, 1024, sbT, sb_b, fin, nullptr, 512, 512, 1024, 2, bn1_g, bn1_b, bn1_m, bn1_v);
        rowdot_k<<<R, 256, 0, stream>>>(fin, df_w, df_b, out + (size_t)b0 * Tz);
    }
}